// Round 1
// baseline (3870.947 us; speedup 1.0000x reference)
//
#include <hip/hip_runtime.h>
#include <math.h>

#define NN 2048
#define DX 3072
#define DE 10
#define NPROBE 32
#define MDEG 64
#define JCH 16      // number of j chunks in cheb gemm
#define JSZ 128     // rows per j chunk
#define ITILE 64

// ---------------- helpers ----------------
__device__ inline float block_reduce_sum256(float v) {
  #pragma unroll
  for (int off = 32; off > 0; off >>= 1) v += __shfl_down(v, off, 64);
  __shared__ float red[4];
  const int lane = threadIdx.x & 63, w = threadIdx.x >> 6;
  if (lane == 0) red[w] = v;
  __syncthreads();
  float r = 0.f;
  if (threadIdx.x == 0) r = red[0] + red[1] + red[2] + red[3];
  return r;  // valid on thread 0 only
}

// ---------------- elementwise prep ----------------
__global__ __launch_bounds__(256) void compute_e_kernel(
    const float* __restrict__ o, const float* __restrict__ tg, float* __restrict__ e) {
  const int idx = blockIdx.x * 256 + threadIdx.x;  // 80*256 = 20480 exact
  e[idx] = o[idx] - tg[idx];
}

__global__ __launch_bounds__(256) void row_sq_kernel(
    const float* __restrict__ x, float* __restrict__ sq) {
  const int i = blockIdx.x, t = threadIdx.x;
  const float4* row = (const float4*)(x + (size_t)i * DX);
  float s = 0.f;
  #pragma unroll
  for (int r = 0; r < 3; r++) {
    float4 v = row[t + 256 * r];
    s += v.x * v.x + v.y * v.y + v.z * v.z + v.w * v.w;
  }
  float tot = block_reduce_sum256(s);
  if (t == 0) sq[i] = tot;
}

__global__ __launch_bounds__(256) void fill_rademacher_kernel(float* __restrict__ v) {
  const unsigned idx = blockIdx.x * 256 + threadIdx.x;  // 256*256 = 65536 exact
  unsigned h = idx * 2654435761u;
  h ^= h >> 16; h *= 0x85ebca6bu; h ^= h >> 13; h *= 0xc2b2ae35u; h ^= h >> 16;
  v[idx] = (h & 1u) ? 1.f : -1.f;
}

__global__ __launch_bounds__(256) void hadamard_kernel(
    float* __restrict__ A, const float* __restrict__ B) {
  const int idx = blockIdx.x * 256 + threadIdx.x;  // 1024 blocks
  float4* a4 = (float4*)A;
  const float4* b4 = (const float4*)B;
  #pragma unroll
  for (int r = 0; r < 4; r++) {
    int k = idx + r * 262144;
    float4 a = a4[k], b = b4[k];
    a.x *= b.x; a.y *= b.y; a.z *= b.z; a.w *= b.w;
    a4[k] = a;
  }
}

// ---------------- Gram matrices ----------------
__global__ __launch_bounds__(256) void gram_x_kernel(
    const float* __restrict__ x, const float* __restrict__ sq, float* __restrict__ K) {
  __shared__ float Al[32][ITILE + 4];
  __shared__ float Bl[32][ITILE + 4];
  const int i0 = blockIdx.x * ITILE, j0 = blockIdx.y * ITILE;
  const int t = threadIdx.x;
  const int lr = t >> 3;          // 0..31
  const int lc = (t & 7) << 2;    // 0,4,...,28
  const int pi = t >> 4, pj = t & 15;
  float acc[4][4] = {};
  for (int k0 = 0; k0 < DX; k0 += 32) {
    float4 a0 = *(const float4*)(x + (size_t)(i0 + lr) * DX + k0 + lc);
    float4 a1 = *(const float4*)(x + (size_t)(i0 + lr + 32) * DX + k0 + lc);
    float4 b0 = *(const float4*)(x + (size_t)(j0 + lr) * DX + k0 + lc);
    float4 b1 = *(const float4*)(x + (size_t)(j0 + lr + 32) * DX + k0 + lc);
    __syncthreads();
    Al[lc + 0][lr] = a0.x; Al[lc + 1][lr] = a0.y; Al[lc + 2][lr] = a0.z; Al[lc + 3][lr] = a0.w;
    Al[lc + 0][lr + 32] = a1.x; Al[lc + 1][lr + 32] = a1.y; Al[lc + 2][lr + 32] = a1.z; Al[lc + 3][lr + 32] = a1.w;
    Bl[lc + 0][lr] = b0.x; Bl[lc + 1][lr] = b0.y; Bl[lc + 2][lr] = b0.z; Bl[lc + 3][lr] = b0.w;
    Bl[lc + 0][lr + 32] = b1.x; Bl[lc + 1][lr + 32] = b1.y; Bl[lc + 2][lr + 32] = b1.z; Bl[lc + 3][lr + 32] = b1.w;
    __syncthreads();
    #pragma unroll
    for (int kk = 0; kk < 32; kk++) {
      float4 av = *(const float4*)&Al[kk][pi << 2];
      float4 bv = *(const float4*)&Bl[kk][pj << 2];
      acc[0][0] = fmaf(av.x, bv.x, acc[0][0]); acc[0][1] = fmaf(av.x, bv.y, acc[0][1]);
      acc[0][2] = fmaf(av.x, bv.z, acc[0][2]); acc[0][3] = fmaf(av.x, bv.w, acc[0][3]);
      acc[1][0] = fmaf(av.y, bv.x, acc[1][0]); acc[1][1] = fmaf(av.y, bv.y, acc[1][1]);
      acc[1][2] = fmaf(av.y, bv.z, acc[1][2]); acc[1][3] = fmaf(av.y, bv.w, acc[1][3]);
      acc[2][0] = fmaf(av.z, bv.x, acc[2][0]); acc[2][1] = fmaf(av.z, bv.y, acc[2][1]);
      acc[2][2] = fmaf(av.z, bv.z, acc[2][2]); acc[2][3] = fmaf(av.z, bv.w, acc[2][3]);
      acc[3][0] = fmaf(av.w, bv.x, acc[3][0]); acc[3][1] = fmaf(av.w, bv.y, acc[3][1]);
      acc[3][2] = fmaf(av.w, bv.z, acc[3][2]); acc[3][3] = fmaf(av.w, bv.w, acc[3][3]);
    }
  }
  const float inv2s2 = 1.0f / 50.0f;  // 1/(2*sigma_x^2), sigma_x=5
  #pragma unroll
  for (int ii = 0; ii < 4; ii++) {
    const int i = i0 + (pi << 2) + ii;
    const float si = sq[i];
    const int jb = j0 + (pj << 2);
    float4 o;
    float d2;
    d2 = fmaxf(si + sq[jb + 0] - 2.f * acc[ii][0], 0.f); o.x = __expf(-d2 * inv2s2);
    d2 = fmaxf(si + sq[jb + 1] - 2.f * acc[ii][1], 0.f); o.y = __expf(-d2 * inv2s2);
    d2 = fmaxf(si + sq[jb + 2] - 2.f * acc[ii][2], 0.f); o.z = __expf(-d2 * inv2s2);
    d2 = fmaxf(si + sq[jb + 3] - 2.f * acc[ii][3], 0.f); o.w = __expf(-d2 * inv2s2);
    *(float4*)(K + (size_t)i * NN + jb) = o;
  }
}

__global__ __launch_bounds__(256) void gram_e_kernel(
    const float* __restrict__ e, float* __restrict__ K) {
  __shared__ float Ei[64][DE];
  __shared__ float Ej[64][DE];
  const int i0 = blockIdx.x * 64, j0 = blockIdx.y * 64;
  const int t = threadIdx.x;
  for (int idx = t; idx < 64 * DE; idx += 256) {
    int r = idx / DE, d = idx - r * DE;
    Ei[r][d] = e[(size_t)(i0 + r) * DE + d];
    Ej[r][d] = e[(size_t)(j0 + r) * DE + d];
  }
  __syncthreads();
  const int pi = t >> 4, pj = t & 15;
  float acc[4][4] = {};
  #pragma unroll
  for (int d = 0; d < DE; d++) {
    float a[4], b[4];
    #pragma unroll
    for (int ii = 0; ii < 4; ii++) a[ii] = Ei[(pi << 2) + ii][d];
    #pragma unroll
    for (int jj = 0; jj < 4; jj++) b[jj] = Ej[(pj << 2) + jj][d];
    #pragma unroll
    for (int ii = 0; ii < 4; ii++)
      #pragma unroll
      for (int jj = 0; jj < 4; jj++) {
        float df = a[ii] - b[jj];
        acc[ii][jj] = fmaf(df, df, acc[ii][jj]);
      }
  }
  #pragma unroll
  for (int ii = 0; ii < 4; ii++) {
    const int i = i0 + (pi << 2) + ii;
    const int jb = j0 + (pj << 2);
    float4 o;
    o.x = __expf(-0.5f * acc[ii][0]);  // sigma_y = 1
    o.y = __expf(-0.5f * acc[ii][1]);
    o.z = __expf(-0.5f * acc[ii][2]);
    o.w = __expf(-0.5f * acc[ii][3]);
    *(float4*)(K + (size_t)i * NN + jb) = o;
  }
}

// ---------------- spectral-range + coefficients ----------------
__global__ __launch_bounds__(256) void rowsum_max_kernel(
    const float* __restrict__ K, unsigned* __restrict__ Rbits) {
  const int i = blockIdx.x, t = threadIdx.x;
  const float4* row = (const float4*)(K + (size_t)i * NN);
  float s = 0.f;
  float4 v = row[t];       s += v.x + v.y + v.z + v.w;
  v = row[t + 256];        s += v.x + v.y + v.z + v.w;
  float tot = block_reduce_sum256(s);
  if (t == 0) atomicMax(Rbits, __float_as_uint(tot));  // rowsums >= 1 > 0: bit-monotone
}

__global__ __launch_bounds__(64) void cheb_coeffs_kernel(
    const unsigned* __restrict__ Rbits, float* __restrict__ c) {
  const int k = threadIdx.x;  // 0..63
  const double R = (double)__uint_as_float(*Rbits);
  const double PI = 3.14159265358979323846;
  double sum = 0.0;
  for (int j = 0; j < 512; j++) {
    double th = PI * (j + 0.5) / 512.0;
    double x = R * (cos(th) + 1.0) * 0.5;
    double f = (x > 0.0) ? x * log(x) : 0.0;
    sum += f * cos(th * (double)k);
  }
  double ck = sum * (2.0 / 512.0);
  if (k == 0) ck *= 0.5;
  c[k] = (float)ck;
}

// ---------------- Chebyshev iteration ----------------
// Partial Y = K * W over a j-chunk; grid (32 i-tiles, 16 j-chunks), 256 threads.
__global__ __launch_bounds__(256) void cheb_gemm_kernel(
    const float* __restrict__ K, const float* __restrict__ W, float* __restrict__ P) {
  __shared__ float Kl[JSZ][ITILE + 4];   // [jj][i], stride 68 (16B aligned)
  __shared__ float Wl[JSZ][NPROBE + 4];  // [jj][p], stride 36 (16B aligned)
  const int i0 = blockIdx.x * ITILE, j0 = blockIdx.y * JSZ;
  const int t = threadIdx.x;
  {
    const int jr = t >> 4, c4 = (t & 15) << 2;
    #pragma unroll
    for (int r = 0; r < 8; r++) {
      int jj = jr + r * 16;
      *(float4*)&Kl[jj][c4] = *(const float4*)(K + (size_t)(j0 + jj) * NN + i0 + c4);
    }
    const int jw = t >> 3, w4 = (t & 7) << 2;
    #pragma unroll
    for (int r = 0; r < 4; r++) {
      int jj = jw + r * 32;
      *(float4*)&Wl[jj][w4] = *(const float4*)(W + (size_t)(j0 + jj) * NPROBE + w4);
    }
  }
  __syncthreads();
  const int ibase = (t >> 4) << 2;  // 4 rows per thread
  const int pbase = (t & 15) << 1;  // 2 probes per thread
  float acc[4][2] = {};
  #pragma unroll 4
  for (int jj = 0; jj < JSZ; jj++) {
    const float4 kv = *(const float4*)&Kl[jj][ibase];
    const float2 wv = *(const float2*)&Wl[jj][pbase];
    acc[0][0] = fmaf(kv.x, wv.x, acc[0][0]); acc[0][1] = fmaf(kv.x, wv.y, acc[0][1]);
    acc[1][0] = fmaf(kv.y, wv.x, acc[1][0]); acc[1][1] = fmaf(kv.y, wv.y, acc[1][1]);
    acc[2][0] = fmaf(kv.z, wv.x, acc[2][0]); acc[2][1] = fmaf(kv.z, wv.y, acc[2][1]);
    acc[3][0] = fmaf(kv.w, wv.x, acc[3][0]); acc[3][1] = fmaf(kv.w, wv.y, acc[3][1]);
  }
  float* Pp = P + (size_t)blockIdx.y * (NN * NPROBE);
  #pragma unroll
  for (int ii = 0; ii < 4; ii++) {
    const int i = i0 + ibase + ii;
    *(float2*)(Pp + (size_t)i * NPROBE + pbase) = make_float2(acc[ii][0], acc[ii][1]);
  }
}

// W_next = (fnum/R)*sum_jc P + beta*W_cur + gamma*W_prev ; S_k += <V, W_next>
__global__ __launch_bounds__(256) void cheb_combine_kernel(
    const float* __restrict__ P, const float* __restrict__ Wcur,
    const float* __restrict__ Wprev, const float* __restrict__ V,
    float* __restrict__ Wnext, const unsigned* __restrict__ Rbits,
    float* __restrict__ Sslot, float fnum, float beta, float gamma) {
  const int idx = blockIdx.x * 256 + threadIdx.x;  // 256*256 = 65536 exact
  const float R = __uint_as_float(*Rbits);
  const float alpha = fnum / R;
  float y = 0.f;
  #pragma unroll
  for (int jc = 0; jc < JCH; jc++) y += P[(size_t)jc * (NN * NPROBE) + idx];
  const float w = alpha * y + beta * Wcur[idx] + gamma * Wprev[idx];
  Wnext[idx] = w;
  float tot = block_reduce_sum256(V[idx] * w);
  if (threadIdx.x == 0) atomicAdd(Sslot, tot);
}

// ---------------- finalize ----------------
__global__ __launch_bounds__(64) void finalize_kernel(
    const float* __restrict__ c, const float* __restrict__ Ssum, float* __restrict__ out) {
  if (threadIdx.x != 0) return;
  double D[3];
  for (int m = 0; m < 3; m++) {
    double d = (double)c[m * MDEG] * (double)(NN * NPROBE);  // S_0 = n*s exactly (Rademacher)
    for (int k = 1; k < MDEG; k++) d += (double)c[m * MDEG + k] * (double)Ssum[m * MDEG + k];
    D[m] = d / (double)(NN * NPROBE);
  }
  // MI = H(Ax) + H(Ae) - H(Axe); H = log n - D
  out[0] = (float)(log((double)NN) - D[0] - D[1] + D[2]);
}

__global__ void fallback_kernel(float* out) { out[0] = logf((float)NN); }

// ---------------- host orchestration ----------------
extern "C" void kernel_launch(void* const* d_in, const int* in_sizes, int n_in,
                              void* d_out, int out_size, void* d_ws, size_t ws_size,
                              hipStream_t stream) {
  const float* x    = (const float*)d_in[0];
  const float* outs = (const float*)d_in[1];
  const float* tgts = (const float*)d_in[2];

  // workspace layout (floats): needs ~39.4 MB
  const size_t NEEDED = (size_t)(1441792 + 2 * NN * NN) * sizeof(float);
  if (ws_size < NEEDED) {  // safety net (stable across calls)
    fallback_kernel<<<1, 64, 0, stream>>>((float*)d_out);
    return;
  }
  float* ws = (float*)d_ws;
  float* Ssum = ws;                         // [3*64]
  unsigned* Rbits = (unsigned*)(ws + 192);  // [3]
  float* cbuf = ws + 256;                   // [3*64]
  float* sqx = ws + 512;                    // [2048]
  float* ebuf = ws + 2560;                  // [20480]
  float* V  = ws + 32768;                   // [65536]
  float* W0 = V + 65536;
  float* W1 = W0 + 65536;
  float* W2 = W1 + 65536;
  float* P  = ws + 294912;                  // [16*65536]
  float* KA = ws + 1441792;                 // [2048*2048]
  float* KB = KA + (size_t)NN * NN;

  hipMemsetAsync(d_ws, 0, 512 * sizeof(float), stream);  // zero S + Rbits
  compute_e_kernel<<<80, 256, 0, stream>>>(outs, tgts, ebuf);
  row_sq_kernel<<<NN, 256, 0, stream>>>(x, sqx);
  gram_x_kernel<<<dim3(32, 32), 256, 0, stream>>>(x, sqx, KA);
  gram_e_kernel<<<dim3(32, 32), 256, 0, stream>>>(ebuf, KB);
  fill_rademacher_kernel<<<256, 256, 0, stream>>>(V);

  auto process = [&](const float* K, int mat) {
    rowsum_max_kernel<<<NN, 256, 0, stream>>>(K, Rbits + mat);
    cheb_coeffs_kernel<<<1, 64, 0, stream>>>(Rbits + mat, cbuf + mat * MDEG);
    fill_rademacher_kernel<<<256, 256, 0, stream>>>(W0);  // W0 = V
    // k = 1: W1 = (2/R) K W0 - W0
    cheb_gemm_kernel<<<dim3(32, 16), 256, 0, stream>>>(K, W0, P);
    cheb_combine_kernel<<<256, 256, 0, stream>>>(P, W0, W0, V, W1, Rbits + mat,
        Ssum + mat * MDEG + 1, 2.f, -1.f, 0.f);
    float *prev = W0, *cur = W1, *nxt = W2;
    for (int k = 2; k < MDEG; k++) {  // W_{k+1} = (4/R) K W_k - 2 W_k - W_{k-1}
      cheb_gemm_kernel<<<dim3(32, 16), 256, 0, stream>>>(K, cur, P);
      cheb_combine_kernel<<<256, 256, 0, stream>>>(P, cur, prev, V, nxt, Rbits + mat,
          Ssum + mat * MDEG + k, 4.f, -2.f, -1.f);
      float* tmp = prev; prev = cur; cur = nxt; nxt = tmp;
    }
  };

  process(KA, 0);                                       // H(Ax)
  process(KB, 1);                                       // H(Ae)
  hadamard_kernel<<<1024, 256, 0, stream>>>(KA, KB);    // KA = Kx o Ke (diag == 1)
  process(KA, 2);                                       // H(Axe)
  finalize_kernel<<<1, 64, 0, stream>>>(cbuf, Ssum, (float*)d_out);
}

// Round 2
// 2560.744 us; speedup vs baseline: 1.5116x; 1.5116x over previous
//
#include <hip/hip_runtime.h>
#include <math.h>

// MILoss via Chebyshev + Hutchinson trace estimation.
// H(A) = log n - tr[g(K)]/n, g(k)=k*ln k, K trace-normalized Gram (diag=1).
// R2: moment-doubling (32 steps -> degree 64), z-batched 3-matrix cheb gemm
// (KC=KA.*KB on the fly), probe-major W (LDS-free gemm), f16-MFMA gram_x.

#define NN 2048
#define DX 3072
#define DE 10
#define SPROBE 16
#define MSTEP 32     // recurrence steps; moments to degree 2*MSTEP = 64
#define NCOEF 65
#define JCHUNK 8
#define JSZ 256
#define CITILE 32

typedef __attribute__((ext_vector_type(8))) _Float16 f16x8;
typedef __attribute__((ext_vector_type(4))) _Float16 f16x4;
typedef __attribute__((ext_vector_type(4))) float f32x4;

// ---------------- helpers ----------------
__device__ inline float block_reduce_sum256(float v) {
  #pragma unroll
  for (int off = 32; off > 0; off >>= 1) v += __shfl_down(v, off, 64);
  __shared__ float red[4];
  const int lane = threadIdx.x & 63, w = threadIdx.x >> 6;
  if (lane == 0) red[w] = v;
  __syncthreads();
  float r = 0.f;
  if (threadIdx.x == 0) r = red[0] + red[1] + red[2] + red[3];
  return r;  // valid on thread 0 only
}

// ---------------- elementwise prep ----------------
__global__ __launch_bounds__(256) void compute_e_kernel(
    const float* __restrict__ o, const float* __restrict__ tg, float* __restrict__ e) {
  const int idx = blockIdx.x * 256 + threadIdx.x;  // 80*256 = 20480 exact
  e[idx] = o[idx] - tg[idx];
}

__global__ __launch_bounds__(256) void row_sq_kernel(
    const float* __restrict__ x, float* __restrict__ sq) {
  const int i = blockIdx.x, t = threadIdx.x;
  const float4* row = (const float4*)(x + (size_t)i * DX);
  float s = 0.f;
  #pragma unroll
  for (int r = 0; r < 3; r++) {
    float4 v = row[t + 256 * r];
    s += v.x * v.x + v.y * v.y + v.z * v.z + v.w * v.w;
  }
  float tot = block_reduce_sum256(s);
  if (t == 0) sq[i] = tot;
}

__global__ __launch_bounds__(256) void fill_rademacher_kernel(float* __restrict__ v) {
  const unsigned idx = blockIdx.x * 256 + threadIdx.x;
  unsigned h = idx * 2654435761u;
  h ^= h >> 16; h *= 0x85ebca6bu; h ^= h >> 13; h *= 0xc2b2ae35u; h ^= h >> 16;
  v[idx] = (h & 1u) ? 1.f : -1.f;
}

// ---------------- gram_x via f16 MFMA (128x128 tile, BK=32) ----------------
__global__ __launch_bounds__(256) void gram_x_mfma_kernel(
    const float* __restrict__ x, const float* __restrict__ sq, float* __restrict__ K) {
  __shared__ _Float16 Ah[128][32];
  __shared__ _Float16 Bh[128][32];
  const int i0 = blockIdx.x * 128, j0 = blockIdx.y * 128;
  const int t = threadIdx.x;
  const int lane = t & 63, w = t >> 6;
  const int wm = (w & 1) * 64, wn = (w >> 1) * 64;
  const int m = lane & 15, q = lane >> 4;
  f32x4 acc[4][4];
  #pragma unroll
  for (int a = 0; a < 4; a++)
    #pragma unroll
    for (int b = 0; b < 4; b++) acc[a][b] = (f32x4){0.f, 0.f, 0.f, 0.f};

  for (int k0 = 0; k0 < DX; k0 += 32) {
    __syncthreads();  // protect previous iteration's readers
    #pragma unroll
    for (int r = 0; r < 4; r++) {
      const int fidx = t + r * 256;
      const int row = fidx >> 3, c4 = (fidx & 7) << 2;
      float4 va = *(const float4*)(x + (size_t)(i0 + row) * DX + k0 + c4);
      float4 vb = *(const float4*)(x + (size_t)(j0 + row) * DX + k0 + c4);
      f16x4 ha = { (_Float16)va.x, (_Float16)va.y, (_Float16)va.z, (_Float16)va.w };
      f16x4 hb = { (_Float16)vb.x, (_Float16)vb.y, (_Float16)vb.z, (_Float16)vb.w };
      *(f16x4*)&Ah[row][c4] = ha;
      *(f16x4*)&Bh[row][c4] = hb;
    }
    __syncthreads();
    f16x8 af[4], bf[4];
    #pragma unroll
    for (int mt = 0; mt < 4; mt++) af[mt] = *(const f16x8*)&Ah[wm + mt * 16 + m][q * 8];
    #pragma unroll
    for (int nt = 0; nt < 4; nt++) bf[nt] = *(const f16x8*)&Bh[wn + nt * 16 + m][q * 8];
    #pragma unroll
    for (int mt = 0; mt < 4; mt++)
      #pragma unroll
      for (int nt = 0; nt < 4; nt++)
        acc[mt][nt] = __builtin_amdgcn_mfma_f32_16x16x32_f16(af[mt], bf[nt], acc[mt][nt], 0, 0, 0);
  }
  // epilogue: d2 = si + sj - 2*dot; K = exp(-d2/50); diag forced to 1 (d_ii==0)
  const float inv2s2 = 0.02f;  // 1/(2*5^2)
  #pragma unroll
  for (int mt = 0; mt < 4; mt++) {
    #pragma unroll
    for (int nt = 0; nt < 4; nt++) {
      const int col = j0 + wn + nt * 16 + m;
      const float sj = sq[col];
      #pragma unroll
      for (int reg = 0; reg < 4; reg++) {
        const int row = i0 + wm + mt * 16 + q * 4 + reg;
        float d2 = fmaxf(sq[row] + sj - 2.0f * acc[mt][nt][reg], 0.f);
        float kv = __expf(-d2 * inv2s2);
        if (row == col) kv = 1.0f;
        K[(size_t)row * NN + col] = kv;
      }
    }
  }
}

// ---------------- gram_e (unchanged from R1, verified) ----------------
__global__ __launch_bounds__(256) void gram_e_kernel(
    const float* __restrict__ e, float* __restrict__ K) {
  __shared__ float Ei[64][DE];
  __shared__ float Ej[64][DE];
  const int i0 = blockIdx.x * 64, j0 = blockIdx.y * 64;
  const int t = threadIdx.x;
  for (int idx = t; idx < 64 * DE; idx += 256) {
    int r = idx / DE, d = idx - r * DE;
    Ei[r][d] = e[(size_t)(i0 + r) * DE + d];
    Ej[r][d] = e[(size_t)(j0 + r) * DE + d];
  }
  __syncthreads();
  const int pi = t >> 4, pj = t & 15;
  float acc[4][4] = {};
  #pragma unroll
  for (int d = 0; d < DE; d++) {
    float a[4], b[4];
    #pragma unroll
    for (int ii = 0; ii < 4; ii++) a[ii] = Ei[(pi << 2) + ii][d];
    #pragma unroll
    for (int jj = 0; jj < 4; jj++) b[jj] = Ej[(pj << 2) + jj][d];
    #pragma unroll
    for (int ii = 0; ii < 4; ii++)
      #pragma unroll
      for (int jj = 0; jj < 4; jj++) {
        float df = a[ii] - b[jj];
        acc[ii][jj] = fmaf(df, df, acc[ii][jj]);
      }
  }
  #pragma unroll
  for (int ii = 0; ii < 4; ii++) {
    const int i = i0 + (pi << 2) + ii;
    const int jb = j0 + (pj << 2);
    float4 o;
    o.x = __expf(-0.5f * acc[ii][0]);  // sigma_y = 1
    o.y = __expf(-0.5f * acc[ii][1]);
    o.z = __expf(-0.5f * acc[ii][2]);
    o.w = __expf(-0.5f * acc[ii][3]);
    *(float4*)(K + (size_t)i * NN + jb) = o;
  }
}

// ---------------- spectral range: 3 row-sum maxima in one pass ----------------
__global__ __launch_bounds__(256) void rowsums3_kernel(
    const float* __restrict__ KA, const float* __restrict__ KB,
    unsigned* __restrict__ Rbits) {
  const int i = blockIdx.x, t = threadIdx.x;
  const float4* ra = (const float4*)(KA + (size_t)i * NN);
  const float4* rb = (const float4*)(KB + (size_t)i * NN);
  float sA = 0, sB = 0, sC = 0;
  #pragma unroll
  for (int r = 0; r < 2; r++) {
    float4 a = ra[t + 256 * r], b = rb[t + 256 * r];
    sA += a.x + a.y + a.z + a.w;
    sB += b.x + b.y + b.z + b.w;
    sC += a.x * b.x + a.y * b.y + a.z * b.z + a.w * b.w;
  }
  #pragma unroll
  for (int off = 32; off > 0; off >>= 1) {
    sA += __shfl_down(sA, off, 64);
    sB += __shfl_down(sB, off, 64);
    sC += __shfl_down(sC, off, 64);
  }
  __shared__ float rA[4], rB[4], rC[4];
  const int lane = t & 63, w = t >> 6;
  if (lane == 0) { rA[w] = sA; rB[w] = sB; rC[w] = sC; }
  __syncthreads();
  if (t == 0) {
    atomicMax(Rbits + 0, __float_as_uint(rA[0] + rA[1] + rA[2] + rA[3]));
    atomicMax(Rbits + 1, __float_as_uint(rB[0] + rB[1] + rB[2] + rB[3]));
    atomicMax(Rbits + 2, __float_as_uint(rC[0] + rC[1] + rC[2] + rC[3]));
  }
}

__global__ __launch_bounds__(128) void cheb_coeffs_kernel(
    const unsigned* __restrict__ Rbits, float* __restrict__ c) {
  const int matm = blockIdx.x;
  const int k = threadIdx.x;
  if (k >= NCOEF) return;
  const double R = (double)__uint_as_float(Rbits[matm]);
  const double PI = 3.14159265358979323846;
  double sum = 0.0;
  for (int jn = 0; jn < 512; jn++) {
    double th = PI * (jn + 0.5) / 512.0;
    double xx = R * (cos(th) + 1.0) * 0.5;
    double f = (xx > 0.0) ? xx * log(xx) : 0.0;
    sum += f * cos(th * (double)k);
  }
  double ck = sum * (2.0 / 512.0);
  if (k == 0) ck *= 0.5;
  c[matm * NCOEF + k] = (float)ck;
}

// ---------------- Chebyshev iteration: z-batched, LDS-free streaming gemm ----
// W layout: [mat][p][j] (probe-major). P layout: [mat][chunk][p][i].
__global__ __launch_bounds__(128) void cheb3_gemm_kernel(
    const float* __restrict__ KA, const float* __restrict__ KB,
    const float* __restrict__ W, float* __restrict__ P) {
  const int mat = blockIdx.z;
  const int i0 = blockIdx.x * CITILE;
  const int j0 = blockIdx.y * JSZ;
  const int t = threadIdx.x;
  const int ig = t >> 3, pg = t & 7;
  const int i = i0 + 2 * ig;
  const int p = 2 * pg;
  const float* Kbase = (mat == 1) ? KB : KA;
  const float* k0p = Kbase + (size_t)i * NN + j0;
  const float* k1p = k0p + NN;
  const float* m0p = KB + (size_t)i * NN + j0;  // only used for mat==2
  const float* m1p = m0p + NN;
  const float* w0p = W + (size_t)mat * (SPROBE * NN) + (size_t)p * NN + j0;
  const float* w1p = w0p + NN;
  float a00 = 0, a01 = 0, a10 = 0, a11 = 0;
  if (mat == 2) {
    #pragma unroll 2
    for (int jj = 0; jj < JSZ; jj += 4) {
      float4 r0 = *(const float4*)(k0p + jj);
      float4 r1 = *(const float4*)(k1p + jj);
      float4 s0 = *(const float4*)(m0p + jj);
      float4 s1 = *(const float4*)(m1p + jj);
      r0.x *= s0.x; r0.y *= s0.y; r0.z *= s0.z; r0.w *= s0.w;
      r1.x *= s1.x; r1.y *= s1.y; r1.z *= s1.z; r1.w *= s1.w;
      float4 u = *(const float4*)(w0p + jj);
      float4 v = *(const float4*)(w1p + jj);
      a00 += r0.x * u.x + r0.y * u.y + r0.z * u.z + r0.w * u.w;
      a01 += r0.x * v.x + r0.y * v.y + r0.z * v.z + r0.w * v.w;
      a10 += r1.x * u.x + r1.y * u.y + r1.z * u.z + r1.w * u.w;
      a11 += r1.x * v.x + r1.y * v.y + r1.z * v.z + r1.w * v.w;
    }
  } else {
    #pragma unroll 2
    for (int jj = 0; jj < JSZ; jj += 4) {
      float4 r0 = *(const float4*)(k0p + jj);
      float4 r1 = *(const float4*)(k1p + jj);
      float4 u = *(const float4*)(w0p + jj);
      float4 v = *(const float4*)(w1p + jj);
      a00 += r0.x * u.x + r0.y * u.y + r0.z * u.z + r0.w * u.w;
      a01 += r0.x * v.x + r0.y * v.y + r0.z * v.z + r0.w * v.w;
      a10 += r1.x * u.x + r1.y * u.y + r1.z * u.z + r1.w * u.w;
      a11 += r1.x * v.x + r1.y * v.y + r1.z * v.z + r1.w * v.w;
    }
  }
  float* Pp = P + ((size_t)mat * JCHUNK + blockIdx.y) * (SPROBE * NN);
  *(float2*)(Pp + (size_t)p * NN + i) = make_float2(a00, a10);
  *(float2*)(Pp + (size_t)(p + 1) * NN + i) = make_float2(a01, a11);
}

// W_next = (fnum/R)*sum_c P + beta*W_cur + gamma*W_prev;
// SsA[k] += <Wnext,Wnext>; SsB[k] += <Wnext,Wcur>   (moment doubling)
__global__ __launch_bounds__(256) void cheb3_combine_kernel(
    const float* __restrict__ P, const float* __restrict__ Wcur,
    const float* __restrict__ Wprev, float* __restrict__ Wnext,
    const unsigned* __restrict__ Rbits, float* __restrict__ SsA,
    float* __restrict__ SsB, int k, float fnum, float beta, float gamma) {
  const int idx = blockIdx.x * 256 + threadIdx.x;  // 384*256 = 98304 exact
  const int mat = idx >> 15;                       // block-uniform (128 blocks/mat)
  const int inner = idx & 32767;
  const float R = __uint_as_float(Rbits[mat]);
  const float alpha = fnum / R;
  float y = 0.f;
  #pragma unroll
  for (int c = 0; c < JCHUNK; c++)
    y += P[((size_t)mat * JCHUNK + c) * (SPROBE * NN) + inner];
  const float wc = Wcur[idx];
  const float wv = alpha * y + beta * wc + gamma * Wprev[idx];
  Wnext[idx] = wv;
  float dA = wv * wv, dB = wv * wc;
  #pragma unroll
  for (int off = 32; off > 0; off >>= 1) {
    dA += __shfl_down(dA, off, 64);
    dB += __shfl_down(dB, off, 64);
  }
  __shared__ float rA[4], rB[4];
  const int lane = threadIdx.x & 63, w = threadIdx.x >> 6;
  if (lane == 0) { rA[w] = dA; rB[w] = dB; }
  __syncthreads();
  if (threadIdx.x == 0) {
    atomicAdd(&SsA[mat * (MSTEP + 1) + k], rA[0] + rA[1] + rA[2] + rA[3]);
    atomicAdd(&SsB[mat * (MSTEP + 1) + k], rB[0] + rB[1] + rB[2] + rB[3]);
  }
}

// ---------------- finalize ----------------
__global__ __launch_bounds__(64) void finalize_kernel(
    const float* __restrict__ c, const float* __restrict__ SsA,
    const float* __restrict__ SsB, float* __restrict__ out) {
  if (threadIdx.x != 0) return;
  const double mu0 = (double)NN * (double)SPROBE;
  double D[3];
  for (int m = 0; m < 3; m++) {
    const float* cm = c + m * NCOEF;
    const double mu1 = (double)SsB[m * (MSTEP + 1) + 1];  // mu1 == B_1
    double d = (double)cm[0] * mu0 + (double)cm[1] * mu1;
    for (int k = 1; k <= MSTEP; k++) {
      const double muE = 2.0 * (double)SsA[m * (MSTEP + 1) + k] - mu0;
      d += (double)cm[2 * k] * muE;
      if (k >= 2) {
        const double muO = 2.0 * (double)SsB[m * (MSTEP + 1) + k] - mu1;
        d += (double)cm[2 * k - 1] * muO;
      }
    }
    D[m] = d / mu0;
  }
  out[0] = (float)(log((double)NN) - D[0] - D[1] + D[2]);
}

__global__ void fallback_kernel(float* out) { out[0] = logf((float)NN); }

// ---------------- host orchestration ----------------
extern "C" void kernel_launch(void* const* d_in, const int* in_sizes, int n_in,
                              void* d_out, int out_size, void* d_ws, size_t ws_size,
                              hipStream_t stream) {
  const float* x    = (const float*)d_in[0];
  const float* outs = (const float*)d_in[1];
  const float* tgts = (const float*)d_in[2];

  // float offsets (total 9,502,720 floats = 38.01 MB)
  const size_t NEEDED = 9502720ull * sizeof(float);
  if (ws_size < NEEDED) {
    fallback_kernel<<<1, 64, 0, stream>>>((float*)d_out);
    return;
  }
  float* ws = (float*)d_ws;
  float* SsA = ws;                           // [3*33] pad to 128
  float* SsB = ws + 128;                     // [3*33] pad to 128
  unsigned* Rbits = (unsigned*)(ws + 256);   // [3] pad to 64
  float* cbuf = ws + 320;                    // [3*65]
  float* sqx  = ws + 576;                    // [2048]
  float* ebuf = ws + 2624;                   // [20480]
  float* W0 = ws + 32768;                    // [3*16*2048] = 98304
  float* W1 = W0 + 98304;
  float* W2 = W1 + 98304;
  float* P  = ws + 327680;                   // [3*8*16*2048] = 786432
  float* KA = ws + 1114112;                  // [2048*2048]
  float* KB = KA + (size_t)NN * NN;          // ends at 9,502,720

  hipMemsetAsync(d_ws, 0, 320 * sizeof(float), stream);  // SsA,SsB,Rbits
  compute_e_kernel<<<80, 256, 0, stream>>>(outs, tgts, ebuf);
  row_sq_kernel<<<NN, 256, 0, stream>>>(x, sqx);
  gram_x_mfma_kernel<<<dim3(16, 16), 256, 0, stream>>>(x, sqx, KA);
  gram_e_kernel<<<dim3(32, 32), 256, 0, stream>>>(ebuf, KB);
  rowsums3_kernel<<<NN, 256, 0, stream>>>(KA, KB, Rbits);
  cheb_coeffs_kernel<<<3, 128, 0, stream>>>(Rbits, cbuf);
  fill_rademacher_kernel<<<384, 256, 0, stream>>>(W0);   // W0 = V (all mats)

  // k = 1: W1 = (2/R) K W0 - W0
  cheb3_gemm_kernel<<<dim3(64, JCHUNK, 3), 128, 0, stream>>>(KA, KB, W0, P);
  cheb3_combine_kernel<<<384, 256, 0, stream>>>(P, W0, W0, W1, Rbits, SsA, SsB,
                                                1, 2.f, -1.f, 0.f);
  float *prev = W0, *cur = W1, *nxt = W2;
  for (int k = 2; k <= MSTEP; k++) {  // W_k = (4/R) K W_{k-1} - 2 W_{k-1} - W_{k-2}
    cheb3_gemm_kernel<<<dim3(64, JCHUNK, 3), 128, 0, stream>>>(KA, KB, cur, P);
    cheb3_combine_kernel<<<384, 256, 0, stream>>>(P, cur, prev, nxt, Rbits, SsA, SsB,
                                                  k, 4.f, -2.f, -1.f);
    float* tmp = prev; prev = cur; cur = nxt; nxt = tmp;
  }
  finalize_kernel<<<1, 64, 0, stream>>>(cbuf, SsA, SsB, (float*)d_out);
}

// Round 3
// 646.949 us; speedup vs baseline: 5.9834x; 3.9582x over previous
//
#include <hip/hip_runtime.h>
#include <math.h>

// MILoss via Chebyshev + Hutchinson trace estimation.
// H(A) = log n - tr[g(K)]/n, g(k)=k*ln k, K trace-normalized Gram (diag=1).
// R3: f16 K storage (KA,KB,KC precomputed), MFMA cheb matvec with fused
// recurrence+dots (1 dispatch/iter), parallelized fp64 coeff kernel.

#define NN 2048
#define DX 3072
#define DE 10
#define SPROBE 16
#define MSTEP 32     // recurrence steps; moments to degree 2*MSTEP = 64
#define NCOEF 65

typedef __attribute__((ext_vector_type(8))) _Float16 f16x8;
typedef __attribute__((ext_vector_type(4))) _Float16 f16x4;
typedef __attribute__((ext_vector_type(4))) float f32x4;

// ---------------- helpers ----------------
__device__ inline float block_reduce_sum256(float v) {
  #pragma unroll
  for (int off = 32; off > 0; off >>= 1) v += __shfl_down(v, off, 64);
  __shared__ float red[4];
  const int lane = threadIdx.x & 63, w = threadIdx.x >> 6;
  if (lane == 0) red[w] = v;
  __syncthreads();
  float r = 0.f;
  if (threadIdx.x == 0) r = red[0] + red[1] + red[2] + red[3];
  return r;  // valid on thread 0 only
}

// ---------------- elementwise prep ----------------
__global__ __launch_bounds__(256) void compute_e_kernel(
    const float* __restrict__ o, const float* __restrict__ tg, float* __restrict__ e) {
  const int idx = blockIdx.x * 256 + threadIdx.x;  // 80*256 = 20480 exact
  e[idx] = o[idx] - tg[idx];
}

__global__ __launch_bounds__(256) void row_sq_kernel(
    const float* __restrict__ x, float* __restrict__ sq) {
  const int i = blockIdx.x, t = threadIdx.x;
  const float4* row = (const float4*)(x + (size_t)i * DX);
  float s = 0.f;
  #pragma unroll
  for (int r = 0; r < 3; r++) {
    float4 v = row[t + 256 * r];
    s += v.x * v.x + v.y * v.y + v.z * v.z + v.w * v.w;
  }
  float tot = block_reduce_sum256(s);
  if (t == 0) sq[i] = tot;
}

__global__ __launch_bounds__(256) void fill_rademacher_kernel(float* __restrict__ v) {
  const unsigned idx = blockIdx.x * 256 + threadIdx.x;  // 384*256 = 98304 exact
  unsigned h = idx * 2654435761u;
  h ^= h >> 16; h *= 0x85ebca6bu; h ^= h >> 13; h *= 0xc2b2ae35u; h ^= h >> 16;
  v[idx] = (h & 1u) ? 1.f : -1.f;
}

// ---------------- gram_x via f16 MFMA (128x128 tile, BK=32), f16 output ----
__global__ __launch_bounds__(256) void gram_x_mfma_kernel(
    const float* __restrict__ x, const float* __restrict__ sq,
    _Float16* __restrict__ K16) {
  __shared__ _Float16 Ah[128][32];
  __shared__ _Float16 Bh[128][32];
  const int i0 = blockIdx.x * 128, j0 = blockIdx.y * 128;
  const int t = threadIdx.x;
  const int lane = t & 63, w = t >> 6;
  const int wm = (w & 1) * 64, wn = (w >> 1) * 64;
  const int m = lane & 15, q = lane >> 4;
  f32x4 acc[4][4];
  #pragma unroll
  for (int a = 0; a < 4; a++)
    #pragma unroll
    for (int b = 0; b < 4; b++) acc[a][b] = (f32x4){0.f, 0.f, 0.f, 0.f};

  for (int k0 = 0; k0 < DX; k0 += 32) {
    __syncthreads();  // protect previous iteration's readers
    #pragma unroll
    for (int r = 0; r < 4; r++) {
      const int fidx = t + r * 256;
      const int row = fidx >> 3, c4 = (fidx & 7) << 2;
      float4 va = *(const float4*)(x + (size_t)(i0 + row) * DX + k0 + c4);
      float4 vb = *(const float4*)(x + (size_t)(j0 + row) * DX + k0 + c4);
      f16x4 ha = { (_Float16)va.x, (_Float16)va.y, (_Float16)va.z, (_Float16)va.w };
      f16x4 hb = { (_Float16)vb.x, (_Float16)vb.y, (_Float16)vb.z, (_Float16)vb.w };
      *(f16x4*)&Ah[row][c4] = ha;
      *(f16x4*)&Bh[row][c4] = hb;
    }
    __syncthreads();
    f16x8 af[4], bf[4];
    #pragma unroll
    for (int mt = 0; mt < 4; mt++) af[mt] = *(const f16x8*)&Ah[wm + mt * 16 + m][q * 8];
    #pragma unroll
    for (int nt = 0; nt < 4; nt++) bf[nt] = *(const f16x8*)&Bh[wn + nt * 16 + m][q * 8];
    #pragma unroll
    for (int mt = 0; mt < 4; mt++)
      #pragma unroll
      for (int nt = 0; nt < 4; nt++)
        acc[mt][nt] = __builtin_amdgcn_mfma_f32_16x16x32_f16(af[mt], bf[nt], acc[mt][nt], 0, 0, 0);
  }
  const float inv2s2 = 0.02f;  // 1/(2*5^2)
  #pragma unroll
  for (int mt = 0; mt < 4; mt++) {
    #pragma unroll
    for (int nt = 0; nt < 4; nt++) {
      const int col = j0 + wn + nt * 16 + m;
      const float sj = sq[col];
      #pragma unroll
      for (int reg = 0; reg < 4; reg++) {
        const int row = i0 + wm + mt * 16 + q * 4 + reg;
        float d2 = fmaxf(sq[row] + sj - 2.0f * acc[mt][nt][reg], 0.f);
        float kv = __expf(-d2 * inv2s2);
        if (row == col) kv = 1.0f;
        K16[(size_t)row * NN + col] = (_Float16)kv;
      }
    }
  }
}

// ---------------- gram_e, f16 output ----------------
__global__ __launch_bounds__(256) void gram_e_kernel(
    const float* __restrict__ e, _Float16* __restrict__ K16) {
  __shared__ float Ei[64][DE];
  __shared__ float Ej[64][DE];
  const int i0 = blockIdx.x * 64, j0 = blockIdx.y * 64;
  const int t = threadIdx.x;
  for (int idx = t; idx < 64 * DE; idx += 256) {
    int r = idx / DE, d = idx - r * DE;
    Ei[r][d] = e[(size_t)(i0 + r) * DE + d];
    Ej[r][d] = e[(size_t)(j0 + r) * DE + d];
  }
  __syncthreads();
  const int pi = t >> 4, pj = t & 15;
  float acc[4][4] = {};
  #pragma unroll
  for (int d = 0; d < DE; d++) {
    float a[4], b[4];
    #pragma unroll
    for (int ii = 0; ii < 4; ii++) a[ii] = Ei[(pi << 2) + ii][d];
    #pragma unroll
    for (int jj = 0; jj < 4; jj++) b[jj] = Ej[(pj << 2) + jj][d];
    #pragma unroll
    for (int ii = 0; ii < 4; ii++)
      #pragma unroll
      for (int jj = 0; jj < 4; jj++) {
        float df = a[ii] - b[jj];
        acc[ii][jj] = fmaf(df, df, acc[ii][jj]);
      }
  }
  #pragma unroll
  for (int ii = 0; ii < 4; ii++) {
    const int i = i0 + (pi << 2) + ii;
    const int jb = j0 + (pj << 2);
    f16x4 o = { (_Float16)__expf(-0.5f * acc[ii][0]),
                (_Float16)__expf(-0.5f * acc[ii][1]),
                (_Float16)__expf(-0.5f * acc[ii][2]),
                (_Float16)__expf(-0.5f * acc[ii][3]) };
    *(f16x4*)(K16 + (size_t)i * NN + jb) = o;
  }
}

// ---------------- KC = KA.*KB + per-row Gershgorin sums (3 mats) ------------
__global__ __launch_bounds__(256) void kc_rowsums_kernel(
    const _Float16* __restrict__ KA16, const _Float16* __restrict__ KB16,
    _Float16* __restrict__ KC16, unsigned* __restrict__ Rbits) {
  const int i = blockIdx.x, t = threadIdx.x;
  const size_t base = (size_t)i * NN + t * 8;
  f16x8 a = *(const f16x8*)(KA16 + base);
  f16x8 b = *(const f16x8*)(KB16 + base);
  f16x8 cp;
  float sA = 0.f, sB = 0.f, sC = 0.f;
  #pragma unroll
  for (int e = 0; e < 8; e++) {
    float fa = (float)a[e], fb = (float)b[e];
    float fc = fa * fb;
    cp[e] = (_Float16)fc;
    sA += fa; sB += fb; sC += fc;
  }
  *(f16x8*)(KC16 + base) = cp;
  #pragma unroll
  for (int off = 32; off > 0; off >>= 1) {
    sA += __shfl_down(sA, off, 64);
    sB += __shfl_down(sB, off, 64);
    sC += __shfl_down(sC, off, 64);
  }
  __shared__ float rA[4], rB[4], rC[4];
  const int lane = t & 63, w = t >> 6;
  if (lane == 0) { rA[w] = sA; rB[w] = sB; rC[w] = sC; }
  __syncthreads();
  if (t == 0) {  // 1.0005 safety: f16 storage rounding + f32 sum rounding
    atomicMax(Rbits + 0, __float_as_uint((rA[0] + rA[1] + rA[2] + rA[3]) * 1.0005f));
    atomicMax(Rbits + 1, __float_as_uint((rB[0] + rB[1] + rB[2] + rB[3]) * 1.0005f));
    atomicMax(Rbits + 2, __float_as_uint((rC[0] + rC[1] + rC[2] + rC[3]) * 1.0005f));
  }
}

// ---------------- Chebyshev coefficients (parallel fp64 DCT) ----------------
__global__ __launch_bounds__(256) void cheb_coeffs_kernel(
    const unsigned* __restrict__ Rbits, float* __restrict__ c) {
  const int bx = blockIdx.x;            // 0..194
  const int matm = bx / NCOEF, k = bx - matm * NCOEF;
  const double R = (double)__uint_as_float(Rbits[matm]);
  const double PI = 3.14159265358979323846;
  const int t = threadIdx.x;
  double sum = 0.0;
  #pragma unroll
  for (int r = 0; r < 2; r++) {
    const int j = t + 256 * r;
    double th = PI * (j + 0.5) / 512.0;
    double xx = R * (cos(th) + 1.0) * 0.5;
    double f = (xx > 0.0) ? xx * log(xx) : 0.0;
    sum += f * cos(th * (double)k);
  }
  #pragma unroll
  for (int off = 32; off > 0; off >>= 1) sum += __shfl_down(sum, off, 64);
  __shared__ double red[4];
  const int lane = t & 63, w = t >> 6;
  if (lane == 0) red[w] = sum;
  __syncthreads();
  if (t == 0) {
    double ck = (red[0] + red[1] + red[2] + red[3]) * (2.0 / 512.0);
    if (k == 0) ck *= 0.5;
    c[matm * NCOEF + k] = (float)ck;
  }
}

// ---------------- fused Chebyshev step ----------------
// Dispatch D_k: reconstruct W_k from Pprev + ring (k>=1), stage to LDS f16,
// compute partial P_k = K * W_k via MFMA. it==0 blocks write W_k to ring and
// accumulate moment dots SsA[k]=<Wk,Wk>, SsB[k]=<Wk,Wk-1>.
// Grid (32 i-tiles x 8 j-chunks x 3 mats), 256 threads (4 waves).
// Ring slot layout: [mat][p][2048] f32 (98304 floats/slot).
// P layout: [mat*8+chunk][p][i] f32.
__global__ __launch_bounds__(256) void cheb_fused_kernel(
    const _Float16* __restrict__ KA16, const _Float16* __restrict__ KB16,
    const _Float16* __restrict__ KC16,
    const float* __restrict__ Pprev, float* __restrict__ Pcur,
    const float* __restrict__ Wcur, const float* __restrict__ Wprev,
    float* __restrict__ Wout,
    const unsigned* __restrict__ Rbits, float* __restrict__ SsA,
    float* __restrict__ SsB, int k, float fnum, float beta, float gamma) {
  __shared__ _Float16 Wlds[16][264];  // pad 8 halves: 528 B stride
  const int mat = blockIdx.z;
  const int i0 = blockIdx.x * 64;
  const int j0 = blockIdx.y * 256;
  const int t = threadIdx.x;
  const int s = t & 15, p = t >> 4;

  if (k > 0) {
    const float R = __uint_as_float(Rbits[mat]);
    const float alpha = fnum / R;
    const size_t wbase = ((size_t)mat * 16 + p) * NN;
    float dA = 0.f, dB = 0.f;
    #pragma unroll
    for (int u = 0; u < 4; u++) {
      const int jl = s * 4 + u * 64;
      const size_t jg = j0 + jl;
      float4 y = {0.f, 0.f, 0.f, 0.f};
      #pragma unroll
      for (int c = 0; c < 8; c++) {
        const float4 pv = *(const float4*)(
            Pprev + (((size_t)(mat * 8 + c) * 16 + p) << 11) + jg);
        y.x += pv.x; y.y += pv.y; y.z += pv.z; y.w += pv.w;
      }
      const float4 wc = *(const float4*)(Wcur + wbase + jg);
      const float4 wp = *(const float4*)(Wprev + wbase + jg);
      float4 wv;
      wv.x = alpha * y.x + beta * wc.x + gamma * wp.x;
      wv.y = alpha * y.y + beta * wc.y + gamma * wp.y;
      wv.z = alpha * y.z + beta * wc.z + gamma * wp.z;
      wv.w = alpha * y.w + beta * wc.w + gamma * wp.w;
      f16x4 h = { (_Float16)wv.x, (_Float16)wv.y, (_Float16)wv.z, (_Float16)wv.w };
      *(f16x4*)&Wlds[p][jl] = h;
      dA += wv.x * wv.x + wv.y * wv.y + wv.z * wv.z + wv.w * wv.w;
      dB += wv.x * wc.x + wv.y * wc.y + wv.z * wc.z + wv.w * wc.w;
      if (blockIdx.x == 0) *(float4*)(Wout + wbase + jg) = wv;
    }
    #pragma unroll
    for (int off = 32; off > 0; off >>= 1) {
      dA += __shfl_down(dA, off, 64);
      dB += __shfl_down(dB, off, 64);
    }
    __shared__ float rA[4], rB[4];
    const int lane = t & 63, w = t >> 6;
    if (lane == 0) { rA[w] = dA; rB[w] = dB; }
    __syncthreads();  // also orders Wlds writes before phase 2
    if (t == 0 && blockIdx.x == 0) {
      atomicAdd(&SsA[mat * (MSTEP + 1) + k], rA[0] + rA[1] + rA[2] + rA[3]);
      atomicAdd(&SsB[mat * (MSTEP + 1) + k], rB[0] + rB[1] + rB[2] + rB[3]);
    }
  } else {
    // k == 0: W_0 = V directly from ring slot (f32 +-1)
    const size_t wbase = ((size_t)mat * 16 + p) * NN;
    #pragma unroll
    for (int u = 0; u < 4; u++) {
      const int jl = s * 4 + u * 64;
      const float4 wv = *(const float4*)(Wcur + wbase + j0 + jl);
      f16x4 h = { (_Float16)wv.x, (_Float16)wv.y, (_Float16)wv.z, (_Float16)wv.w };
      *(f16x4*)&Wlds[p][jl] = h;
    }
    __syncthreads();
  }

  // phase 2: MFMA gemm over this (i-tile, j-chunk)
  const int w = t >> 6, lane = t & 63;
  const int m = lane & 15, q = lane >> 4;
  const _Float16* Kp = (mat == 0) ? KA16 : ((mat == 1) ? KB16 : KC16);
  const size_t rowoff = (size_t)(i0 + w * 16 + m) * NN + j0;
  f32x4 acc = {0.f, 0.f, 0.f, 0.f};
  #pragma unroll
  for (int st = 0; st < 8; st++) {
    const int jb = st * 32 + q * 8;
    f16x8 a = *(const f16x8*)(Kp + rowoff + jb);
    f16x8 b = *(const f16x8*)&Wlds[m][jb];
    acc = __builtin_amdgcn_mfma_f32_16x16x32_f16(a, b, acc, 0, 0, 0);
  }
  float4 stv = {acc[0], acc[1], acc[2], acc[3]};
  *(float4*)(Pcur + (((size_t)(mat * 8 + blockIdx.y) * 16 + m) << 11) +
             i0 + w * 16 + q * 4) = stv;
}

// ---------------- tail: dots for k = 32 (no gemm) ----------------
__global__ __launch_bounds__(256) void cheb_tail_kernel(
    const float* __restrict__ P, const float* __restrict__ Wcur,
    const float* __restrict__ Wprev, const unsigned* __restrict__ Rbits,
    float* __restrict__ SsA, float* __restrict__ SsB) {
  const int idx = blockIdx.x * 256 + threadIdx.x;  // 384*256 = 98304 exact
  const int mat = idx >> 15;
  const int inner = idx & 32767;
  const float R = __uint_as_float(Rbits[mat]);
  const float alpha = 4.f / R;
  float y = 0.f;
  #pragma unroll
  for (int c = 0; c < 8; c++) y += P[(((size_t)mat * 8 + c) << 15) + inner];
  const float wc = Wcur[idx];
  const float wv = alpha * y - 2.f * wc - Wprev[idx];
  float dA = wv * wv, dB = wv * wc;
  #pragma unroll
  for (int off = 32; off > 0; off >>= 1) {
    dA += __shfl_down(dA, off, 64);
    dB += __shfl_down(dB, off, 64);
  }
  __shared__ float rA[4], rB[4];
  const int lane = threadIdx.x & 63, w = threadIdx.x >> 6;
  if (lane == 0) { rA[w] = dA; rB[w] = dB; }
  __syncthreads();
  if (threadIdx.x == 0) {
    atomicAdd(&SsA[mat * (MSTEP + 1) + MSTEP], rA[0] + rA[1] + rA[2] + rA[3]);
    atomicAdd(&SsB[mat * (MSTEP + 1) + MSTEP], rB[0] + rB[1] + rB[2] + rB[3]);
  }
}

// ---------------- finalize ----------------
__global__ __launch_bounds__(64) void finalize_kernel(
    const float* __restrict__ c, const float* __restrict__ SsA,
    const float* __restrict__ SsB, float* __restrict__ out) {
  if (threadIdx.x != 0) return;
  const double mu0 = (double)NN * (double)SPROBE;
  double D[3];
  for (int m = 0; m < 3; m++) {
    const float* cm = c + m * NCOEF;
    const double mu1 = (double)SsB[m * (MSTEP + 1) + 1];  // mu1 == <W1,W0>
    double d = (double)cm[0] * mu0 + (double)cm[1] * mu1;
    for (int k = 1; k <= MSTEP; k++) {
      const double muE = 2.0 * (double)SsA[m * (MSTEP + 1) + k] - mu0;
      d += (double)cm[2 * k] * muE;
      if (k >= 2) {
        const double muO = 2.0 * (double)SsB[m * (MSTEP + 1) + k] - mu1;
        d += (double)cm[2 * k - 1] * muO;
      }
    }
    D[m] = d / mu0;
  }
  out[0] = (float)(log((double)NN) - D[0] - D[1] + D[2]);
}

__global__ void fallback_kernel(float* out) { out[0] = logf((float)NN); }

// ---------------- host orchestration ----------------
extern "C" void kernel_launch(void* const* d_in, const int* in_sizes, int n_in,
                              void* d_out, int out_size, void* d_ws, size_t ws_size,
                              hipStream_t stream) {
  const float* x    = (const float*)d_in[0];
  const float* outs = (const float*)d_in[1];
  const float* tgts = (const float*)d_in[2];

  // float-unit offsets; total 8,192,000 floats = 32.77 MB
  const size_t NEEDED = 8192000ull * sizeof(float);
  if (ws_size < NEEDED) {
    fallback_kernel<<<1, 64, 0, stream>>>((float*)d_out);
    return;
  }
  float* ws = (float*)d_ws;
  float* SsA = ws;                           // [3*33] pad 128
  float* SsB = ws + 128;                     // [3*33] pad 128
  unsigned* Rbits = (unsigned*)(ws + 256);   // [3] pad 32
  float* cbuf = ws + 288;                    // [3*65=195] -> ends 483
  float* sqx  = ws + 512;                    // [2048]
  float* ebuf = ws + 2560;                   // [20480] -> ends 23040
  float* Wring = ws + 32768;                 // 3 slots x 98304 -> ends 327680
  float* Pb[2] = { ws + 327680, ws + 1114112 };  // 2 x 786432 -> ends 1900544
  _Float16* KA16 = (_Float16*)(ws + 1900544);    // 3 x 4194304 halves
  _Float16* KB16 = KA16 + (size_t)NN * NN;
  _Float16* KC16 = KB16 + (size_t)NN * NN;

  hipMemsetAsync(d_ws, 0, 1152, stream);  // SsA, SsB, Rbits
  compute_e_kernel<<<80, 256, 0, stream>>>(outs, tgts, ebuf);
  row_sq_kernel<<<NN, 256, 0, stream>>>(x, sqx);
  gram_x_mfma_kernel<<<dim3(16, 16), 256, 0, stream>>>(x, sqx, KA16);
  gram_e_kernel<<<dim3(32, 32), 256, 0, stream>>>(ebuf, KB16);
  kc_rowsums_kernel<<<NN, 256, 0, stream>>>(KA16, KB16, KC16, Rbits);
  cheb_coeffs_kernel<<<3 * NCOEF, 256, 0, stream>>>(Rbits, cbuf);
  fill_rademacher_kernel<<<384, 256, 0, stream>>>(Wring);  // ring slot 0 = W_0

  for (int k = 0; k < MSTEP; k++) {
    const float fnum  = (k == 1) ? 2.f : 4.f;
    const float beta  = (k == 1) ? -1.f : -2.f;
    const float gamma = (k <= 1) ? 0.f : -1.f;
    const int scur = (k == 0) ? 0 : (k - 1) % 3;      // W_{k-1} slot (W_0 for k=0)
    const int sprev = (k <= 1) ? 0 : (k - 2) % 3;     // W_{k-2} slot (dummy if gamma=0)
    cheb_fused_kernel<<<dim3(32, 8, 3), 256, 0, stream>>>(
        KA16, KB16, KC16, Pb[(k + 1) & 1], Pb[k & 1],
        Wring + (size_t)scur * 98304, Wring + (size_t)sprev * 98304,
        Wring + (size_t)(k % 3) * 98304,
        Rbits, SsA, SsB, k, fnum, beta, gamma);
  }
  // k = 32 dots from P_31 (in Pb[1]), W_31 = ring[31%3=1], W_30 = ring[0]
  cheb_tail_kernel<<<384, 256, 0, stream>>>(
      Pb[1], Wring + 98304, Wring, Rbits, SsA, SsB);
  finalize_kernel<<<1, 64, 0, stream>>>(cbuf, SsA, SsB, (float*)d_out);
}

// Round 4
// 400.644 us; speedup vs baseline: 9.6618x; 1.6148x over previous
//
#include <hip/hip_runtime.h>
#include <math.h>

// MILoss via Chebyshev + Hutchinson trace estimation.
// H(A) = log n - tr[g(K)]/n, g(k)=k*ln k, K trace-normalized Gram (diag=1).
// R4: MSTEP=16 (degree-32 via moment doubling), symmetric gram_x with f16
// pre-converted X + BK=64 + padded LDS (kills bank conflicts), JCHUNK=4
// fused cheb step (halves redundant P-reconstruction traffic).

#define NN 2048
#define DX 3072
#define DE 10
#define SPROBE 16
#define MSTEP 16     // recurrence steps; moments to degree 2*MSTEP = 32
#define NCOEF 33     // 2*MSTEP + 1
#define JCHUNK 4
#define JSZ 512

typedef __attribute__((ext_vector_type(8))) _Float16 f16x8;
typedef __attribute__((ext_vector_type(4))) _Float16 f16x4;
typedef __attribute__((ext_vector_type(4))) float f32x4;

// ---------------- helpers ----------------
__device__ inline float block_reduce_sum256(float v) {
  #pragma unroll
  for (int off = 32; off > 0; off >>= 1) v += __shfl_down(v, off, 64);
  __shared__ float red[4];
  const int lane = threadIdx.x & 63, w = threadIdx.x >> 6;
  if (lane == 0) red[w] = v;
  __syncthreads();
  float r = 0.f;
  if (threadIdx.x == 0) r = red[0] + red[1] + red[2] + red[3];
  return r;  // valid on thread 0 only
}

// ---------------- elementwise prep ----------------
__global__ __launch_bounds__(256) void compute_e_kernel(
    const float* __restrict__ o, const float* __restrict__ tg, float* __restrict__ e) {
  const int idx = blockIdx.x * 256 + threadIdx.x;  // 80*256 = 20480 exact
  e[idx] = o[idx] - tg[idx];
}

__global__ __launch_bounds__(256) void row_sq_kernel(
    const float* __restrict__ x, float* __restrict__ sq) {
  const int i = blockIdx.x, t = threadIdx.x;
  const float4* row = (const float4*)(x + (size_t)i * DX);
  float s = 0.f;
  #pragma unroll
  for (int r = 0; r < 3; r++) {
    float4 v = row[t + 256 * r];
    s += v.x * v.x + v.y * v.y + v.z * v.z + v.w * v.w;
  }
  float tot = block_reduce_sum256(s);
  if (t == 0) sq[i] = tot;
}

__global__ __launch_bounds__(256) void x_to_f16_kernel(
    const float* __restrict__ x, _Float16* __restrict__ Xh) {
  const int idx = blockIdx.x * 256 + threadIdx.x;  // 6144*256 = 1572864 exact
  float4 v = ((const float4*)x)[idx];
  f16x4 h = { (_Float16)v.x, (_Float16)v.y, (_Float16)v.z, (_Float16)v.w };
  ((f16x4*)Xh)[idx] = h;
}

__global__ __launch_bounds__(256) void fill_rademacher_kernel(float* __restrict__ v) {
  const unsigned idx = blockIdx.x * 256 + threadIdx.x;  // 384*256 = 98304 exact
  unsigned h = idx * 2654435761u;
  h ^= h >> 16; h *= 0x85ebca6bu; h ^= h >> 13; h *= 0xc2b2ae35u; h ^= h >> 16;
  v[idx] = (h & 1u) ? 1.f : -1.f;
}

// ------- gram_x: symmetric, f16 input, 128x128 tile, BK=64, padded LDS -------
__global__ __launch_bounds__(256) void gram_x_mfma_kernel(
    const _Float16* __restrict__ Xh, const float* __restrict__ sq,
    _Float16* __restrict__ K16) {
  const int bi = blockIdx.x, bj = blockIdx.y;
  if (bj < bi) return;  // symmetry: compute upper triangle only
  __shared__ _Float16 Ah[128][72];  // 144 B row stride: 16B-aligned, conflict-free
  __shared__ _Float16 Bh[128][72];
  const int i0 = bi * 128, j0 = bj * 128;
  const int t = threadIdx.x;
  const int lane = t & 63, w = t >> 6;
  const int wm = (w & 1) * 64, wn = (w >> 1) * 64;
  const int m = lane & 15, q = lane >> 4;
  f32x4 acc[4][4];
  #pragma unroll
  for (int a = 0; a < 4; a++)
    #pragma unroll
    for (int b = 0; b < 4; b++) acc[a][b] = (f32x4){0.f, 0.f, 0.f, 0.f};

  for (int k0 = 0; k0 < DX; k0 += 64) {
    __syncthreads();  // protect previous round's readers
    #pragma unroll
    for (int r = 0; r < 4; r++) {
      const int fidx = t + r * 256;
      const int row = fidx >> 3, c8 = (fidx & 7) << 3;
      f16x8 va = *(const f16x8*)(Xh + (size_t)(i0 + row) * DX + k0 + c8);
      f16x8 vb = *(const f16x8*)(Xh + (size_t)(j0 + row) * DX + k0 + c8);
      *(f16x8*)&Ah[row][c8] = va;
      *(f16x8*)&Bh[row][c8] = vb;
    }
    __syncthreads();
    #pragma unroll
    for (int sub = 0; sub < 2; sub++) {
      f16x8 af[4], bf[4];
      #pragma unroll
      for (int mt = 0; mt < 4; mt++)
        af[mt] = *(const f16x8*)&Ah[wm + mt * 16 + m][sub * 32 + q * 8];
      #pragma unroll
      for (int nt = 0; nt < 4; nt++)
        bf[nt] = *(const f16x8*)&Bh[wn + nt * 16 + m][sub * 32 + q * 8];
      #pragma unroll
      for (int mt = 0; mt < 4; mt++)
        #pragma unroll
        for (int nt = 0; nt < 4; nt++)
          acc[mt][nt] = __builtin_amdgcn_mfma_f32_16x16x32_f16(af[mt], bf[nt], acc[mt][nt], 0, 0, 0);
    }
  }
  const float inv2s2 = 0.02f;  // 1/(2*5^2)
  #pragma unroll
  for (int mt = 0; mt < 4; mt++) {
    #pragma unroll
    for (int nt = 0; nt < 4; nt++) {
      const int col = j0 + wn + nt * 16 + m;
      const float sj = sq[col];
      #pragma unroll
      for (int reg = 0; reg < 4; reg++) {
        const int row = i0 + wm + mt * 16 + q * 4 + reg;
        float d2 = fmaxf(sq[row] + sj - 2.0f * acc[mt][nt][reg], 0.f);
        float kv = __expf(-d2 * inv2s2);
        if (row == col) kv = 1.0f;
        K16[(size_t)row * NN + col] = (_Float16)kv;
        if (bi != bj) K16[(size_t)col * NN + row] = (_Float16)kv;  // mirror
      }
    }
  }
}

// ---------------- gram_e, f16 output ----------------
__global__ __launch_bounds__(256) void gram_e_kernel(
    const float* __restrict__ e, _Float16* __restrict__ K16) {
  __shared__ float Ei[64][DE];
  __shared__ float Ej[64][DE];
  const int i0 = blockIdx.x * 64, j0 = blockIdx.y * 64;
  const int t = threadIdx.x;
  for (int idx = t; idx < 64 * DE; idx += 256) {
    int r = idx / DE, d = idx - r * DE;
    Ei[r][d] = e[(size_t)(i0 + r) * DE + d];
    Ej[r][d] = e[(size_t)(j0 + r) * DE + d];
  }
  __syncthreads();
  const int pi = t >> 4, pj = t & 15;
  float acc[4][4] = {};
  #pragma unroll
  for (int d = 0; d < DE; d++) {
    float a[4], b[4];
    #pragma unroll
    for (int ii = 0; ii < 4; ii++) a[ii] = Ei[(pi << 2) + ii][d];
    #pragma unroll
    for (int jj = 0; jj < 4; jj++) b[jj] = Ej[(pj << 2) + jj][d];
    #pragma unroll
    for (int ii = 0; ii < 4; ii++)
      #pragma unroll
      for (int jj = 0; jj < 4; jj++) {
        float df = a[ii] - b[jj];
        acc[ii][jj] = fmaf(df, df, acc[ii][jj]);
      }
  }
  #pragma unroll
  for (int ii = 0; ii < 4; ii++) {
    const int i = i0 + (pi << 2) + ii;
    const int jb = j0 + (pj << 2);
    f16x4 o = { (_Float16)__expf(-0.5f * acc[ii][0]),
                (_Float16)__expf(-0.5f * acc[ii][1]),
                (_Float16)__expf(-0.5f * acc[ii][2]),
                (_Float16)__expf(-0.5f * acc[ii][3]) };
    *(f16x4*)(K16 + (size_t)i * NN + jb) = o;
  }
}

// ---------------- KC = KA.*KB + per-row Gershgorin sums (3 mats) ------------
__global__ __launch_bounds__(256) void kc_rowsums_kernel(
    const _Float16* __restrict__ KA16, const _Float16* __restrict__ KB16,
    _Float16* __restrict__ KC16, unsigned* __restrict__ Rbits) {
  const int i = blockIdx.x, t = threadIdx.x;
  const size_t base = (size_t)i * NN + t * 8;
  f16x8 a = *(const f16x8*)(KA16 + base);
  f16x8 b = *(const f16x8*)(KB16 + base);
  f16x8 cp;
  float sA = 0.f, sB = 0.f, sC = 0.f;
  #pragma unroll
  for (int e = 0; e < 8; e++) {
    float fa = (float)a[e], fb = (float)b[e];
    float fc = fa * fb;
    cp[e] = (_Float16)fc;
    sA += fa; sB += fb; sC += fc;
  }
  *(f16x8*)(KC16 + base) = cp;
  #pragma unroll
  for (int off = 32; off > 0; off >>= 1) {
    sA += __shfl_down(sA, off, 64);
    sB += __shfl_down(sB, off, 64);
    sC += __shfl_down(sC, off, 64);
  }
  __shared__ float rA[4], rB[4], rC[4];
  const int lane = t & 63, w = t >> 6;
  if (lane == 0) { rA[w] = sA; rB[w] = sB; rC[w] = sC; }
  __syncthreads();
  if (t == 0) {  // 1.0005 safety: f16 storage rounding + f32 sum rounding
    atomicMax(Rbits + 0, __float_as_uint((rA[0] + rA[1] + rA[2] + rA[3]) * 1.0005f));
    atomicMax(Rbits + 1, __float_as_uint((rB[0] + rB[1] + rB[2] + rB[3]) * 1.0005f));
    atomicMax(Rbits + 2, __float_as_uint((rC[0] + rC[1] + rC[2] + rC[3]) * 1.0005f));
  }
}

// ---------------- Chebyshev coefficients (parallel fp64 DCT) ----------------
__global__ __launch_bounds__(256) void cheb_coeffs_kernel(
    const unsigned* __restrict__ Rbits, float* __restrict__ c) {
  const int bx = blockIdx.x;  // 0 .. 3*NCOEF-1
  const int matm = bx / NCOEF, k = bx - matm * NCOEF;
  const double R = (double)__uint_as_float(Rbits[matm]);
  const double PI = 3.14159265358979323846;
  const int t = threadIdx.x;
  double sum = 0.0;
  #pragma unroll
  for (int r = 0; r < 2; r++) {
    const int j = t + 256 * r;
    double th = PI * (j + 0.5) / 512.0;
    double xx = R * (cos(th) + 1.0) * 0.5;
    double f = (xx > 0.0) ? xx * log(xx) : 0.0;
    sum += f * cos(th * (double)k);
  }
  #pragma unroll
  for (int off = 32; off > 0; off >>= 1) sum += __shfl_down(sum, off, 64);
  __shared__ double red[4];
  const int lane = t & 63, w = t >> 6;
  if (lane == 0) red[w] = sum;
  __syncthreads();
  if (t == 0) {
    double ck = (red[0] + red[1] + red[2] + red[3]) * (2.0 / 512.0);
    if (k == 0) ck *= 0.5;
    c[matm * NCOEF + k] = (float)ck;
  }
}

// ---------------- fused Chebyshev step ----------------
// Dispatch D_k: reconstruct W_k from Pprev + ring (k>=1), stage to LDS f16,
// compute partial P_k = K * W_k via MFMA. blockIdx.x==0 blocks write W_k to
// ring and accumulate SsA[k]=<Wk,Wk>, SsB[k]=<Wk,Wk-1> (moment doubling).
// Grid (32 i-tiles x 4 j-chunks x 3 mats), 256 threads.
// Ring slot: [mat][p][2048] f32 (98304/slot). P: [mat*4+chunk][p][i] f32.
__global__ __launch_bounds__(256) void cheb_fused_kernel(
    const _Float16* __restrict__ KA16, const _Float16* __restrict__ KB16,
    const _Float16* __restrict__ KC16,
    const float* __restrict__ Pprev, float* __restrict__ Pcur,
    const float* __restrict__ Wcur, const float* __restrict__ Wprev,
    float* __restrict__ Wout,
    const unsigned* __restrict__ Rbits, float* __restrict__ SsA,
    float* __restrict__ SsB, int k, float fnum, float beta, float gamma) {
  __shared__ _Float16 Wlds[16][520];  // 1040 B stride (16B-aligned, 2-way banks)
  const int mat = blockIdx.z;
  const int i0 = blockIdx.x * 64;
  const int j0 = blockIdx.y * JSZ;
  const int t = threadIdx.x;
  const int s = t & 15, p = t >> 4;

  if (k > 0) {
    const float R = __uint_as_float(Rbits[mat]);
    const float alpha = fnum / R;
    const size_t wbase = ((size_t)mat * 16 + p) * NN;
    float dA = 0.f, dB = 0.f;
    #pragma unroll
    for (int u = 0; u < 8; u++) {
      const int jl = s * 4 + u * 64;
      const size_t jg = j0 + jl;
      float4 y = {0.f, 0.f, 0.f, 0.f};
      #pragma unroll
      for (int c = 0; c < JCHUNK; c++) {
        const float4 pv = *(const float4*)(
            Pprev + (((size_t)(mat * JCHUNK + c) * 16 + p) << 11) + jg);
        y.x += pv.x; y.y += pv.y; y.z += pv.z; y.w += pv.w;
      }
      const float4 wc = *(const float4*)(Wcur + wbase + jg);
      const float4 wp = *(const float4*)(Wprev + wbase + jg);
      float4 wv;
      wv.x = alpha * y.x + beta * wc.x + gamma * wp.x;
      wv.y = alpha * y.y + beta * wc.y + gamma * wp.y;
      wv.z = alpha * y.z + beta * wc.z + gamma * wp.z;
      wv.w = alpha * y.w + beta * wc.w + gamma * wp.w;
      f16x4 h = { (_Float16)wv.x, (_Float16)wv.y, (_Float16)wv.z, (_Float16)wv.w };
      *(f16x4*)&Wlds[p][jl] = h;
      dA += wv.x * wv.x + wv.y * wv.y + wv.z * wv.z + wv.w * wv.w;
      dB += wv.x * wc.x + wv.y * wc.y + wv.z * wc.z + wv.w * wc.w;
      if (blockIdx.x == 0) *(float4*)(Wout + wbase + jg) = wv;
    }
    #pragma unroll
    for (int off = 32; off > 0; off >>= 1) {
      dA += __shfl_down(dA, off, 64);
      dB += __shfl_down(dB, off, 64);
    }
    __shared__ float rA[4], rB[4];
    const int lane = t & 63, w = t >> 6;
    if (lane == 0) { rA[w] = dA; rB[w] = dB; }
    __syncthreads();  // also orders Wlds writes before phase 2
    if (t == 0 && blockIdx.x == 0) {
      atomicAdd(&SsA[mat * (MSTEP + 1) + k], rA[0] + rA[1] + rA[2] + rA[3]);
      atomicAdd(&SsB[mat * (MSTEP + 1) + k], rB[0] + rB[1] + rB[2] + rB[3]);
    }
  } else {
    // k == 0: W_0 = V directly from ring slot (f32 +-1)
    const size_t wbase = ((size_t)mat * 16 + p) * NN;
    #pragma unroll
    for (int u = 0; u < 8; u++) {
      const int jl = s * 4 + u * 64;
      const float4 wv = *(const float4*)(Wcur + wbase + j0 + jl);
      f16x4 h = { (_Float16)wv.x, (_Float16)wv.y, (_Float16)wv.z, (_Float16)wv.w };
      *(f16x4*)&Wlds[p][jl] = h;
    }
    __syncthreads();
  }

  // phase 2: MFMA gemm over this (i-tile, j-chunk)
  const int w = t >> 6, lane = t & 63;
  const int m = lane & 15, q = lane >> 4;
  const _Float16* Kp = (mat == 0) ? KA16 : ((mat == 1) ? KB16 : KC16);
  const size_t rowoff = (size_t)(i0 + w * 16 + m) * NN + j0;
  f32x4 acc = {0.f, 0.f, 0.f, 0.f};
  #pragma unroll
  for (int st = 0; st < 16; st++) {
    const int jb = st * 32 + q * 8;
    f16x8 a = *(const f16x8*)(Kp + rowoff + jb);
    f16x8 b = *(const f16x8*)&Wlds[m][jb];
    acc = __builtin_amdgcn_mfma_f32_16x16x32_f16(a, b, acc, 0, 0, 0);
  }
  float4 stv = {acc[0], acc[1], acc[2], acc[3]};
  *(float4*)(Pcur + (((size_t)(mat * JCHUNK + blockIdx.y) * 16 + m) << 11) +
             i0 + w * 16 + q * 4) = stv;
}

// ---------------- tail: dots for k = MSTEP (no gemm) ----------------
__global__ __launch_bounds__(256) void cheb_tail_kernel(
    const float* __restrict__ P, const float* __restrict__ Wcur,
    const float* __restrict__ Wprev, const unsigned* __restrict__ Rbits,
    float* __restrict__ SsA, float* __restrict__ SsB) {
  const int idx = blockIdx.x * 256 + threadIdx.x;  // 384*256 = 98304 exact
  const int mat = idx >> 15;
  const int inner = idx & 32767;
  const float R = __uint_as_float(Rbits[mat]);
  const float alpha = 4.f / R;
  float y = 0.f;
  #pragma unroll
  for (int c = 0; c < JCHUNK; c++)
    y += P[(((size_t)mat * JCHUNK + c) << 15) + inner];
  const float wc = Wcur[idx];
  const float wv = alpha * y - 2.f * wc - Wprev[idx];
  float dA = wv * wv, dB = wv * wc;
  #pragma unroll
  for (int off = 32; off > 0; off >>= 1) {
    dA += __shfl_down(dA, off, 64);
    dB += __shfl_down(dB, off, 64);
  }
  __shared__ float rA[4], rB[4];
  const int lane = threadIdx.x & 63, w = threadIdx.x >> 6;
  if (lane == 0) { rA[w] = dA; rB[w] = dB; }
  __syncthreads();
  if (threadIdx.x == 0) {
    atomicAdd(&SsA[mat * (MSTEP + 1) + MSTEP], rA[0] + rA[1] + rA[2] + rA[3]);
    atomicAdd(&SsB[mat * (MSTEP + 1) + MSTEP], rB[0] + rB[1] + rB[2] + rB[3]);
  }
}

// ---------------- finalize ----------------
__global__ __launch_bounds__(64) void finalize_kernel(
    const float* __restrict__ c, const float* __restrict__ SsA,
    const float* __restrict__ SsB, float* __restrict__ out) {
  if (threadIdx.x != 0) return;
  const double mu0 = (double)NN * (double)SPROBE;
  double D[3];
  for (int m = 0; m < 3; m++) {
    const float* cm = c + m * NCOEF;
    const double mu1 = (double)SsB[m * (MSTEP + 1) + 1];  // mu1 == <W1,W0>
    double d = (double)cm[0] * mu0 + (double)cm[1] * mu1;
    for (int k = 1; k <= MSTEP; k++) {
      const double muE = 2.0 * (double)SsA[m * (MSTEP + 1) + k] - mu0;
      d += (double)cm[2 * k] * muE;
      if (k >= 2) {
        const double muO = 2.0 * (double)SsB[m * (MSTEP + 1) + k] - mu1;
        d += (double)cm[2 * k - 1] * muO;
      }
    }
    D[m] = d / mu0;
  }
  out[0] = (float)(log((double)NN) - D[0] - D[1] + D[2]);
}

__global__ void fallback_kernel(float* out) { out[0] = logf((float)NN); }

// ---------------- host orchestration ----------------
extern "C" void kernel_launch(void* const* d_in, const int* in_sizes, int n_in,
                              void* d_out, int out_size, void* d_ws, size_t ws_size,
                              hipStream_t stream) {
  const float* x    = (const float*)d_in[0];
  const float* outs = (const float*)d_in[1];
  const float* tgts = (const float*)d_in[2];

  // float-unit offsets; total 8,454,144 floats = 33.8 MB
  const size_t NEEDED = 8454144ull * sizeof(float);
  if (ws_size < NEEDED) {
    fallback_kernel<<<1, 64, 0, stream>>>((float*)d_out);
    return;
  }
  float* ws = (float*)d_ws;
  float* SsA = ws;                           // [3*17] pad 128
  float* SsB = ws + 128;                     // [3*17] pad 128
  unsigned* Rbits = (unsigned*)(ws + 256);   // [3] pad 32
  float* cbuf = ws + 288;                    // [3*33=99] -> ends 387
  float* sqx  = ws + 512;                    // [2048]
  float* ebuf = ws + 2560;                   // [20480] -> ends 23040
  float* Wring = ws + 32768;                 // 3 slots x 98304 -> ends 327680
  float* Pb[2] = { ws + 327680, ws + 720896 };  // 2 x 393216 -> ends 1114112
  _Float16* Xh = (_Float16*)(ws + 1114112);     // 6291456 halves (3145728 f)
  _Float16* KC16 = Xh;                          // aliases Xh (Xh dead by then)
  _Float16* KA16 = (_Float16*)(ws + 4259840);   // 4194304 halves each
  _Float16* KB16 = KA16 + (size_t)NN * NN;      // ends 8454144

  hipMemsetAsync(d_ws, 0, 1152, stream);  // SsA, SsB, Rbits
  compute_e_kernel<<<80, 256, 0, stream>>>(outs, tgts, ebuf);
  row_sq_kernel<<<NN, 256, 0, stream>>>(x, sqx);
  x_to_f16_kernel<<<6144, 256, 0, stream>>>(x, Xh);
  gram_x_mfma_kernel<<<dim3(16, 16), 256, 0, stream>>>(Xh, sqx, KA16);
  gram_e_kernel<<<dim3(32, 32), 256, 0, stream>>>(ebuf, KB16);
  kc_rowsums_kernel<<<NN, 256, 0, stream>>>(KA16, KB16, KC16, Rbits);
  cheb_coeffs_kernel<<<3 * NCOEF, 256, 0, stream>>>(Rbits, cbuf);
  fill_rademacher_kernel<<<384, 256, 0, stream>>>(Wring);  // ring slot 0 = W_0

  for (int k = 0; k < MSTEP; k++) {
    const float fnum  = (k == 1) ? 2.f : 4.f;
    const float beta  = (k == 1) ? -1.f : -2.f;
    const float gamma = (k <= 1) ? 0.f : -1.f;
    const int scur = (k == 0) ? 0 : (k - 1) % 3;   // W_{k-1} slot (W_0 for k=0)
    const int sprev = (k <= 1) ? 0 : (k - 2) % 3;  // W_{k-2} slot (dummy if gamma=0)
    cheb_fused_kernel<<<dim3(32, JCHUNK, 3), 256, 0, stream>>>(
        KA16, KB16, KC16, Pb[(k + 1) & 1], Pb[k & 1],
        Wring + (size_t)scur * 98304, Wring + (size_t)sprev * 98304,
        Wring + (size_t)(k % 3) * 98304,
        Rbits, SsA, SsB, k, fnum, beta, gamma);
  }
  // tail k=16: P_15 in Pb[15&1]=Pb[1]; W_15 = ring[15%3=0], W_14 = ring[14%3=2]
  cheb_tail_kernel<<<384, 256, 0, stream>>>(
      Pb[1], Wring, Wring + 2 * 98304, Rbits, SsA, SsB);
  finalize_kernel<<<1, 64, 0, stream>>>(cbuf, SsA, SsB, (float*)d_out);
}

// Round 5
// 354.898 us; speedup vs baseline: 10.9072x; 1.1289x over previous
//
#include <hip/hip_runtime.h>
#include <math.h>

// MILoss via Chebyshev + Hutchinson trace estimation.
// H(A) = log n - tr[g(K)]/n, g(k)=k*ln k, K trace-normalized Gram (diag=1).
// R5: atomic-free Gershgorin row-sum max (75us atomicMax serialization ->
// two-stage reduce), JCHUNK=8 cheb step (768 blocks = 12 waves/CU).

#define NN 2048
#define DX 3072
#define DE 10
#define SPROBE 16
#define MSTEP 16     // recurrence steps; moments to degree 2*MSTEP = 32
#define NCOEF 33     // 2*MSTEP + 1
#define JCHUNK 8
#define JSZ 256

typedef __attribute__((ext_vector_type(8))) _Float16 f16x8;
typedef __attribute__((ext_vector_type(4))) _Float16 f16x4;
typedef __attribute__((ext_vector_type(4))) float f32x4;

// ---------------- helpers ----------------
__device__ inline float block_reduce_sum256(float v) {
  #pragma unroll
  for (int off = 32; off > 0; off >>= 1) v += __shfl_down(v, off, 64);
  __shared__ float red[4];
  const int lane = threadIdx.x & 63, w = threadIdx.x >> 6;
  if (lane == 0) red[w] = v;
  __syncthreads();
  float r = 0.f;
  if (threadIdx.x == 0) r = red[0] + red[1] + red[2] + red[3];
  return r;  // valid on thread 0 only
}

// ---------------- elementwise prep ----------------
__global__ __launch_bounds__(256) void compute_e_kernel(
    const float* __restrict__ o, const float* __restrict__ tg, float* __restrict__ e) {
  const int idx = blockIdx.x * 256 + threadIdx.x;  // 80*256 = 20480 exact
  e[idx] = o[idx] - tg[idx];
}

__global__ __launch_bounds__(256) void row_sq_kernel(
    const float* __restrict__ x, float* __restrict__ sq) {
  const int i = blockIdx.x, t = threadIdx.x;
  const float4* row = (const float4*)(x + (size_t)i * DX);
  float s = 0.f;
  #pragma unroll
  for (int r = 0; r < 3; r++) {
    float4 v = row[t + 256 * r];
    s += v.x * v.x + v.y * v.y + v.z * v.z + v.w * v.w;
  }
  float tot = block_reduce_sum256(s);
  if (t == 0) sq[i] = tot;
}

__global__ __launch_bounds__(256) void x_to_f16_kernel(
    const float* __restrict__ x, _Float16* __restrict__ Xh) {
  const int idx = blockIdx.x * 256 + threadIdx.x;  // 6144*256 = 1572864 exact
  float4 v = ((const float4*)x)[idx];
  f16x4 h = { (_Float16)v.x, (_Float16)v.y, (_Float16)v.z, (_Float16)v.w };
  ((f16x4*)Xh)[idx] = h;
}

__global__ __launch_bounds__(256) void fill_rademacher_kernel(float* __restrict__ v) {
  const unsigned idx = blockIdx.x * 256 + threadIdx.x;  // 384*256 = 98304 exact
  unsigned h = idx * 2654435761u;
  h ^= h >> 16; h *= 0x85ebca6bu; h ^= h >> 13; h *= 0xc2b2ae35u; h ^= h >> 16;
  v[idx] = (h & 1u) ? 1.f : -1.f;
}

// ------- gram_x: symmetric, f16 input, 128x128 tile, BK=64, padded LDS -------
__global__ __launch_bounds__(256) void gram_x_mfma_kernel(
    const _Float16* __restrict__ Xh, const float* __restrict__ sq,
    _Float16* __restrict__ K16) {
  const int bi = blockIdx.x, bj = blockIdx.y;
  if (bj < bi) return;  // symmetry: compute upper triangle only
  __shared__ _Float16 Ah[128][72];  // 144 B row stride: 16B-aligned, conflict-free
  __shared__ _Float16 Bh[128][72];
  const int i0 = bi * 128, j0 = bj * 128;
  const int t = threadIdx.x;
  const int lane = t & 63, w = t >> 6;
  const int wm = (w & 1) * 64, wn = (w >> 1) * 64;
  const int m = lane & 15, q = lane >> 4;
  f32x4 acc[4][4];
  #pragma unroll
  for (int a = 0; a < 4; a++)
    #pragma unroll
    for (int b = 0; b < 4; b++) acc[a][b] = (f32x4){0.f, 0.f, 0.f, 0.f};

  for (int k0 = 0; k0 < DX; k0 += 64) {
    __syncthreads();  // protect previous round's readers
    #pragma unroll
    for (int r = 0; r < 4; r++) {
      const int fidx = t + r * 256;
      const int row = fidx >> 3, c8 = (fidx & 7) << 3;
      f16x8 va = *(const f16x8*)(Xh + (size_t)(i0 + row) * DX + k0 + c8);
      f16x8 vb = *(const f16x8*)(Xh + (size_t)(j0 + row) * DX + k0 + c8);
      *(f16x8*)&Ah[row][c8] = va;
      *(f16x8*)&Bh[row][c8] = vb;
    }
    __syncthreads();
    #pragma unroll
    for (int sub = 0; sub < 2; sub++) {
      f16x8 af[4], bf[4];
      #pragma unroll
      for (int mt = 0; mt < 4; mt++)
        af[mt] = *(const f16x8*)&Ah[wm + mt * 16 + m][sub * 32 + q * 8];
      #pragma unroll
      for (int nt = 0; nt < 4; nt++)
        bf[nt] = *(const f16x8*)&Bh[wn + nt * 16 + m][sub * 32 + q * 8];
      #pragma unroll
      for (int mt = 0; mt < 4; mt++)
        #pragma unroll
        for (int nt = 0; nt < 4; nt++)
          acc[mt][nt] = __builtin_amdgcn_mfma_f32_16x16x32_f16(af[mt], bf[nt], acc[mt][nt], 0, 0, 0);
    }
  }
  const float inv2s2 = 0.02f;  // 1/(2*5^2)
  #pragma unroll
  for (int mt = 0; mt < 4; mt++) {
    #pragma unroll
    for (int nt = 0; nt < 4; nt++) {
      const int col = j0 + wn + nt * 16 + m;
      const float sj = sq[col];
      #pragma unroll
      for (int reg = 0; reg < 4; reg++) {
        const int row = i0 + wm + mt * 16 + q * 4 + reg;
        float d2 = fmaxf(sq[row] + sj - 2.0f * acc[mt][nt][reg], 0.f);
        float kv = __expf(-d2 * inv2s2);
        if (row == col) kv = 1.0f;
        K16[(size_t)row * NN + col] = (_Float16)kv;
        if (bi != bj) K16[(size_t)col * NN + row] = (_Float16)kv;  // mirror
      }
    }
  }
}

// ---------------- gram_e, f16 output ----------------
__global__ __launch_bounds__(256) void gram_e_kernel(
    const float* __restrict__ e, _Float16* __restrict__ K16) {
  __shared__ float Ei[64][DE];
  __shared__ float Ej[64][DE];
  const int i0 = blockIdx.x * 64, j0 = blockIdx.y * 64;
  const int t = threadIdx.x;
  for (int idx = t; idx < 64 * DE; idx += 256) {
    int r = idx / DE, d = idx - r * DE;
    Ei[r][d] = e[(size_t)(i0 + r) * DE + d];
    Ej[r][d] = e[(size_t)(j0 + r) * DE + d];
  }
  __syncthreads();
  const int pi = t >> 4, pj = t & 15;
  float acc[4][4] = {};
  #pragma unroll
  for (int d = 0; d < DE; d++) {
    float a[4], b[4];
    #pragma unroll
    for (int ii = 0; ii < 4; ii++) a[ii] = Ei[(pi << 2) + ii][d];
    #pragma unroll
    for (int jj = 0; jj < 4; jj++) b[jj] = Ej[(pj << 2) + jj][d];
    #pragma unroll
    for (int ii = 0; ii < 4; ii++)
      #pragma unroll
      for (int jj = 0; jj < 4; jj++) {
        float df = a[ii] - b[jj];
        acc[ii][jj] = fmaf(df, df, acc[ii][jj]);
      }
  }
  #pragma unroll
  for (int ii = 0; ii < 4; ii++) {
    const int i = i0 + (pi << 2) + ii;
    const int jb = j0 + (pj << 2);
    f16x4 o = { (_Float16)__expf(-0.5f * acc[ii][0]),
                (_Float16)__expf(-0.5f * acc[ii][1]),
                (_Float16)__expf(-0.5f * acc[ii][2]),
                (_Float16)__expf(-0.5f * acc[ii][3]) };
    *(f16x4*)(K16 + (size_t)i * NN + jb) = o;
  }
}

// ------- KC = KA.*KB + per-row Gershgorin sums (atomic-free, 3 mats) --------
__global__ __launch_bounds__(256) void kc_rowsums_kernel(
    const _Float16* __restrict__ KA16, const _Float16* __restrict__ KB16,
    _Float16* __restrict__ KC16, float* __restrict__ rows) {
  const int i = blockIdx.x, t = threadIdx.x;
  const size_t base = (size_t)i * NN + t * 8;
  f16x8 a = *(const f16x8*)(KA16 + base);
  f16x8 b = *(const f16x8*)(KB16 + base);
  f16x8 cp;
  float sA = 0.f, sB = 0.f, sC = 0.f;
  #pragma unroll
  for (int e = 0; e < 8; e++) {
    float fa = (float)a[e], fb = (float)b[e];
    float fc = fa * fb;
    cp[e] = (_Float16)fc;
    sA += fa; sB += fb; sC += fc;
  }
  *(f16x8*)(KC16 + base) = cp;
  #pragma unroll
  for (int off = 32; off > 0; off >>= 1) {
    sA += __shfl_down(sA, off, 64);
    sB += __shfl_down(sB, off, 64);
    sC += __shfl_down(sC, off, 64);
  }
  __shared__ float rA[4], rB[4], rC[4];
  const int lane = t & 63, w = t >> 6;
  if (lane == 0) { rA[w] = sA; rB[w] = sB; rC[w] = sC; }
  __syncthreads();
  if (t == 0) {
    rows[i]            = rA[0] + rA[1] + rA[2] + rA[3];
    rows[NN + i]       = rB[0] + rB[1] + rB[2] + rB[3];
    rows[2 * NN + i]   = rC[0] + rC[1] + rC[2] + rC[3];
  }
}

// single block: max over per-row sums -> Gershgorin radii
__global__ __launch_bounds__(256) void rmax_kernel(
    const float* __restrict__ rows, unsigned* __restrict__ Rbits) {
  const int t = threadIdx.x;
  float m0 = 0.f, m1 = 0.f, m2 = 0.f;
  for (int i = t; i < NN; i += 256) {
    m0 = fmaxf(m0, rows[i]);
    m1 = fmaxf(m1, rows[NN + i]);
    m2 = fmaxf(m2, rows[2 * NN + i]);
  }
  #pragma unroll
  for (int off = 32; off > 0; off >>= 1) {
    m0 = fmaxf(m0, __shfl_down(m0, off, 64));
    m1 = fmaxf(m1, __shfl_down(m1, off, 64));
    m2 = fmaxf(m2, __shfl_down(m2, off, 64));
  }
  __shared__ float rA[4], rB[4], rC[4];
  const int lane = t & 63, w = t >> 6;
  if (lane == 0) { rA[w] = m0; rB[w] = m1; rC[w] = m2; }
  __syncthreads();
  if (t == 0) {  // 1.0005 safety: f16 storage rounding + f32 sum rounding
    Rbits[0] = __float_as_uint(fmaxf(fmaxf(rA[0], rA[1]), fmaxf(rA[2], rA[3])) * 1.0005f);
    Rbits[1] = __float_as_uint(fmaxf(fmaxf(rB[0], rB[1]), fmaxf(rB[2], rB[3])) * 1.0005f);
    Rbits[2] = __float_as_uint(fmaxf(fmaxf(rC[0], rC[1]), fmaxf(rC[2], rC[3])) * 1.0005f);
  }
}

// ---------------- Chebyshev coefficients (parallel fp64 DCT) ----------------
__global__ __launch_bounds__(256) void cheb_coeffs_kernel(
    const unsigned* __restrict__ Rbits, float* __restrict__ c) {
  const int bx = blockIdx.x;  // 0 .. 3*NCOEF-1
  const int matm = bx / NCOEF, k = bx - matm * NCOEF;
  const double R = (double)__uint_as_float(Rbits[matm]);
  const double PI = 3.14159265358979323846;
  const int t = threadIdx.x;
  double sum = 0.0;
  #pragma unroll
  for (int r = 0; r < 2; r++) {
    const int j = t + 256 * r;
    double th = PI * (j + 0.5) / 512.0;
    double xx = R * (cos(th) + 1.0) * 0.5;
    double f = (xx > 0.0) ? xx * log(xx) : 0.0;
    sum += f * cos(th * (double)k);
  }
  #pragma unroll
  for (int off = 32; off > 0; off >>= 1) sum += __shfl_down(sum, off, 64);
  __shared__ double red[4];
  const int lane = t & 63, w = t >> 6;
  if (lane == 0) red[w] = sum;
  __syncthreads();
  if (t == 0) {
    double ck = (red[0] + red[1] + red[2] + red[3]) * (2.0 / 512.0);
    if (k == 0) ck *= 0.5;
    c[matm * NCOEF + k] = (float)ck;
  }
}

// ---------------- fused Chebyshev step ----------------
// Dispatch D_k: reconstruct W_k from Pprev + ring (k>=1), stage to LDS f16,
// compute partial P_k = K * W_k via MFMA. blockIdx.x==0 blocks write W_k to
// ring and accumulate SsA[k]=<Wk,Wk>, SsB[k]=<Wk,Wk-1> (moment doubling).
// Grid (32 i-tiles x 8 j-chunks x 3 mats) = 768 blocks, 256 threads.
// Ring slot: [mat][p][2048] f32 (98304/slot). P: [mat*8+chunk][p][i] f32.
__global__ __launch_bounds__(256) void cheb_fused_kernel(
    const _Float16* __restrict__ KA16, const _Float16* __restrict__ KB16,
    const _Float16* __restrict__ KC16,
    const float* __restrict__ Pprev, float* __restrict__ Pcur,
    const float* __restrict__ Wcur, const float* __restrict__ Wprev,
    float* __restrict__ Wout,
    const unsigned* __restrict__ Rbits, float* __restrict__ SsA,
    float* __restrict__ SsB, int k, float fnum, float beta, float gamma) {
  __shared__ _Float16 Wlds[16][264];  // 528 B stride (16B-aligned)
  const int mat = blockIdx.z;
  const int i0 = blockIdx.x * 64;
  const int j0 = blockIdx.y * JSZ;
  const int t = threadIdx.x;
  const int s = t & 15, p = t >> 4;

  if (k > 0) {
    const float R = __uint_as_float(Rbits[mat]);
    const float alpha = fnum / R;
    const size_t wbase = ((size_t)mat * 16 + p) * NN;
    float dA = 0.f, dB = 0.f;
    #pragma unroll
    for (int u = 0; u < 4; u++) {
      const int jl = s * 4 + u * 64;
      const size_t jg = j0 + jl;
      float4 y = {0.f, 0.f, 0.f, 0.f};
      #pragma unroll
      for (int c = 0; c < JCHUNK; c++) {
        const float4 pv = *(const float4*)(
            Pprev + (((size_t)(mat * JCHUNK + c) * 16 + p) << 11) + jg);
        y.x += pv.x; y.y += pv.y; y.z += pv.z; y.w += pv.w;
      }
      const float4 wc = *(const float4*)(Wcur + wbase + jg);
      const float4 wp = *(const float4*)(Wprev + wbase + jg);
      float4 wv;
      wv.x = alpha * y.x + beta * wc.x + gamma * wp.x;
      wv.y = alpha * y.y + beta * wc.y + gamma * wp.y;
      wv.z = alpha * y.z + beta * wc.z + gamma * wp.z;
      wv.w = alpha * y.w + beta * wc.w + gamma * wp.w;
      f16x4 h = { (_Float16)wv.x, (_Float16)wv.y, (_Float16)wv.z, (_Float16)wv.w };
      *(f16x4*)&Wlds[p][jl] = h;
      dA += wv.x * wv.x + wv.y * wv.y + wv.z * wv.z + wv.w * wv.w;
      dB += wv.x * wc.x + wv.y * wc.y + wv.z * wc.z + wv.w * wc.w;
      if (blockIdx.x == 0) *(float4*)(Wout + wbase + jg) = wv;
    }
    #pragma unroll
    for (int off = 32; off > 0; off >>= 1) {
      dA += __shfl_down(dA, off, 64);
      dB += __shfl_down(dB, off, 64);
    }
    __shared__ float rA[4], rB[4];
    const int lane = t & 63, w = t >> 6;
    if (lane == 0) { rA[w] = dA; rB[w] = dB; }
    __syncthreads();  // also orders Wlds writes before phase 2
    if (t == 0 && blockIdx.x == 0) {
      atomicAdd(&SsA[mat * (MSTEP + 1) + k], rA[0] + rA[1] + rA[2] + rA[3]);
      atomicAdd(&SsB[mat * (MSTEP + 1) + k], rB[0] + rB[1] + rB[2] + rB[3]);
    }
  } else {
    // k == 0: W_0 = V directly from ring slot (f32 +-1)
    const size_t wbase = ((size_t)mat * 16 + p) * NN;
    #pragma unroll
    for (int u = 0; u < 4; u++) {
      const int jl = s * 4 + u * 64;
      const float4 wv = *(const float4*)(Wcur + wbase + j0 + jl);
      f16x4 h = { (_Float16)wv.x, (_Float16)wv.y, (_Float16)wv.z, (_Float16)wv.w };
      *(f16x4*)&Wlds[p][jl] = h;
    }
    __syncthreads();
  }

  // phase 2: MFMA gemm over this (i-tile, j-chunk)
  const int w = t >> 6, lane = t & 63;
  const int m = lane & 15, q = lane >> 4;
  const _Float16* Kp = (mat == 0) ? KA16 : ((mat == 1) ? KB16 : KC16);
  const size_t rowoff = (size_t)(i0 + w * 16 + m) * NN + j0;
  f32x4 acc = {0.f, 0.f, 0.f, 0.f};
  #pragma unroll
  for (int st = 0; st < 8; st++) {
    const int jb = st * 32 + q * 8;
    f16x8 a = *(const f16x8*)(Kp + rowoff + jb);
    f16x8 b = *(const f16x8*)&Wlds[m][jb];
    acc = __builtin_amdgcn_mfma_f32_16x16x32_f16(a, b, acc, 0, 0, 0);
  }
  float4 stv = {acc[0], acc[1], acc[2], acc[3]};
  *(float4*)(Pcur + (((size_t)(mat * JCHUNK + blockIdx.y) * 16 + m) << 11) +
             i0 + w * 16 + q * 4) = stv;
}

// ---------------- tail: dots for k = MSTEP (no gemm) ----------------
__global__ __launch_bounds__(256) void cheb_tail_kernel(
    const float* __restrict__ P, const float* __restrict__ Wcur,
    const float* __restrict__ Wprev, const unsigned* __restrict__ Rbits,
    float* __restrict__ SsA, float* __restrict__ SsB) {
  const int idx = blockIdx.x * 256 + threadIdx.x;  // 384*256 = 98304 exact
  const int mat = idx >> 15;
  const int inner = idx & 32767;
  const float R = __uint_as_float(Rbits[mat]);
  const float alpha = 4.f / R;
  float y = 0.f;
  #pragma unroll
  for (int c = 0; c < JCHUNK; c++)
    y += P[(((size_t)mat * JCHUNK + c) << 15) + inner];
  const float wc = Wcur[idx];
  const float wv = alpha * y - 2.f * wc - Wprev[idx];
  float dA = wv * wv, dB = wv * wc;
  #pragma unroll
  for (int off = 32; off > 0; off >>= 1) {
    dA += __shfl_down(dA, off, 64);
    dB += __shfl_down(dB, off, 64);
  }
  __shared__ float rA[4], rB[4];
  const int lane = threadIdx.x & 63, w = threadIdx.x >> 6;
  if (lane == 0) { rA[w] = dA; rB[w] = dB; }
  __syncthreads();
  if (threadIdx.x == 0) {
    atomicAdd(&SsA[mat * (MSTEP + 1) + MSTEP], rA[0] + rA[1] + rA[2] + rA[3]);
    atomicAdd(&SsB[mat * (MSTEP + 1) + MSTEP], rB[0] + rB[1] + rB[2] + rB[3]);
  }
}

// ---------------- finalize ----------------
__global__ __launch_bounds__(64) void finalize_kernel(
    const float* __restrict__ c, const float* __restrict__ SsA,
    const float* __restrict__ SsB, float* __restrict__ out) {
  if (threadIdx.x != 0) return;
  const double mu0 = (double)NN * (double)SPROBE;
  double D[3];
  for (int m = 0; m < 3; m++) {
    const float* cm = c + m * NCOEF;
    const double mu1 = (double)SsB[m * (MSTEP + 1) + 1];  // mu1 == <W1,W0>
    double d = (double)cm[0] * mu0 + (double)cm[1] * mu1;
    for (int k = 1; k <= MSTEP; k++) {
      const double muE = 2.0 * (double)SsA[m * (MSTEP + 1) + k] - mu0;
      d += (double)cm[2 * k] * muE;
      if (k >= 2) {
        const double muO = 2.0 * (double)SsB[m * (MSTEP + 1) + k] - mu1;
        d += (double)cm[2 * k - 1] * muO;
      }
    }
    D[m] = d / mu0;
  }
  out[0] = (float)(log((double)NN) - D[0] - D[1] + D[2]);
}

__global__ void fallback_kernel(float* out) { out[0] = logf((float)NN); }

// ---------------- host orchestration ----------------
extern "C" void kernel_launch(void* const* d_in, const int* in_sizes, int n_in,
                              void* d_out, int out_size, void* d_ws, size_t ws_size,
                              hipStream_t stream) {
  const float* x    = (const float*)d_in[0];
  const float* outs = (const float*)d_in[1];
  const float* tgts = (const float*)d_in[2];

  // float-unit offsets; total 9,240,576 floats = 36.96 MB
  const size_t NEEDED = 9240576ull * sizeof(float);
  if (ws_size < NEEDED) {
    fallback_kernel<<<1, 64, 0, stream>>>((float*)d_out);
    return;
  }
  float* ws = (float*)d_ws;
  float* SsA = ws;                           // [3*17] pad 128
  float* SsB = ws + 128;                     // [3*17] pad 128
  unsigned* Rbits = (unsigned*)(ws + 256);   // [3] pad 32
  float* cbuf = ws + 288;                    // [3*33=99] -> ends 387
  float* sqx  = ws + 512;                    // [2048]
  float* ebuf = ws + 2560;                   // [20480] -> ends 23040
  float* rows = ws + 24576;                  // [3*2048] -> ends 30720
  float* Wring = ws + 32768;                 // 3 x 98304 -> ends 327680
  float* Pb[2] = { ws + 327680, ws + 1114112 };  // 2 x 786432 -> ends 1900544
  _Float16* Xh = (_Float16*)(ws + 1900544);      // 6291456 halves (3145728 f)
  _Float16* KC16 = Xh;                           // aliases Xh (Xh dead by then)
  _Float16* KA16 = (_Float16*)(ws + 5046272);    // 4194304 halves each
  _Float16* KB16 = KA16 + (size_t)NN * NN;       // ends 9240576

  hipMemsetAsync(d_ws, 0, 1152, stream);  // SsA, SsB, Rbits
  compute_e_kernel<<<80, 256, 0, stream>>>(outs, tgts, ebuf);
  row_sq_kernel<<<NN, 256, 0, stream>>>(x, sqx);
  x_to_f16_kernel<<<6144, 256, 0, stream>>>(x, Xh);
  gram_x_mfma_kernel<<<dim3(16, 16), 256, 0, stream>>>(Xh, sqx, KA16);
  gram_e_kernel<<<dim3(32, 32), 256, 0, stream>>>(ebuf, KB16);
  kc_rowsums_kernel<<<NN, 256, 0, stream>>>(KA16, KB16, KC16, rows);
  rmax_kernel<<<1, 256, 0, stream>>>(rows, Rbits);
  cheb_coeffs_kernel<<<3 * NCOEF, 256, 0, stream>>>(Rbits, cbuf);
  fill_rademacher_kernel<<<384, 256, 0, stream>>>(Wring);  // ring slot 0 = W_0

  for (int k = 0; k < MSTEP; k++) {
    const float fnum  = (k == 1) ? 2.f : 4.f;
    const float beta  = (k == 1) ? -1.f : -2.f;
    const float gamma = (k <= 1) ? 0.f : -1.f;
    const int scur = (k == 0) ? 0 : (k - 1) % 3;   // W_{k-1} slot (W_0 for k=0)
    const int sprev = (k <= 1) ? 0 : (k - 2) % 3;  // W_{k-2} slot (dummy if gamma=0)
    cheb_fused_kernel<<<dim3(32, JCHUNK, 3), 256, 0, stream>>>(
        KA16, KB16, KC16, Pb[(k + 1) & 1], Pb[k & 1],
        Wring + (size_t)scur * 98304, Wring + (size_t)sprev * 98304,
        Wring + (size_t)(k % 3) * 98304,
        Rbits, SsA, SsB, k, fnum, beta, gamma);
  }
  // tail k=16: P_15 in Pb[15&1]=Pb[1]; W_15 = ring[15%3=0], W_14 = ring[14%3=2]
  cheb_tail_kernel<<<384, 256, 0, stream>>>(
      Pb[1], Wring, Wring + 2 * 98304, Rbits, SsA, SsB);
  finalize_kernel<<<1, 64, 0, stream>>>(cbuf, SsA, SsB, (float*)d_out);
}

// Round 6
// 243.487 us; speedup vs baseline: 15.8980x; 1.4576x over previous
//
#include <hip/hip_runtime.h>
#include <math.h>

// MILoss via Chebyshev + Hutchinson trace estimation.
// H(A) = log n - tr[g(K)]/n, g(k)=k*ln k, K trace-normalized Gram (diag=1).
// R6: gram_x 64x64 tiles (528 working blocks vs 136 -> TLP hides staging),
// MSTEP=8 (deg-16; spectrum clustered near 1, deg-32/64 gave identical error),
// fused row_sq + f16 convert.

#define NN 2048
#define DX 3072
#define DE 10
#define SPROBE 16
#define MSTEP 8      // recurrence steps; moments to degree 2*MSTEP = 16
#define NCOEF 17     // 2*MSTEP + 1
#define JCHUNK 8
#define JSZ 256

typedef __attribute__((ext_vector_type(8))) _Float16 f16x8;
typedef __attribute__((ext_vector_type(4))) _Float16 f16x4;
typedef __attribute__((ext_vector_type(4))) float f32x4;

// ---------------- helpers ----------------
__device__ inline float block_reduce_sum256(float v) {
  #pragma unroll
  for (int off = 32; off > 0; off >>= 1) v += __shfl_down(v, off, 64);
  __shared__ float red[4];
  const int lane = threadIdx.x & 63, w = threadIdx.x >> 6;
  if (lane == 0) red[w] = v;
  __syncthreads();
  float r = 0.f;
  if (threadIdx.x == 0) r = red[0] + red[1] + red[2] + red[3];
  return r;  // valid on thread 0 only
}

// ---------------- elementwise prep ----------------
__global__ __launch_bounds__(256) void compute_e_kernel(
    const float* __restrict__ o, const float* __restrict__ tg, float* __restrict__ e) {
  const int idx = blockIdx.x * 256 + threadIdx.x;  // 80*256 = 20480 exact
  e[idx] = o[idx] - tg[idx];
}

// fused: row squared-norms + f32->f16 convert (single pass over x)
__global__ __launch_bounds__(256) void prep_x_kernel(
    const float* __restrict__ x, float* __restrict__ sq, _Float16* __restrict__ Xh) {
  const int i = blockIdx.x, t = threadIdx.x;
  const float4* row = (const float4*)(x + (size_t)i * DX);
  f16x4* out = (f16x4*)(Xh + (size_t)i * DX);
  float s = 0.f;
  #pragma unroll
  for (int r = 0; r < 3; r++) {
    const int f4 = t + 256 * r;
    float4 v = row[f4];
    s += v.x * v.x + v.y * v.y + v.z * v.z + v.w * v.w;
    f16x4 h = { (_Float16)v.x, (_Float16)v.y, (_Float16)v.z, (_Float16)v.w };
    out[f4] = h;
  }
  float tot = block_reduce_sum256(s);
  if (t == 0) sq[i] = tot;
}

__global__ __launch_bounds__(256) void fill_rademacher_kernel(float* __restrict__ v) {
  const unsigned idx = blockIdx.x * 256 + threadIdx.x;  // 384*256 = 98304 exact
  unsigned h = idx * 2654435761u;
  h ^= h >> 16; h *= 0x85ebca6bu; h ^= h >> 13; h *= 0xc2b2ae35u; h ^= h >> 16;
  v[idx] = (h & 1u) ? 1.f : -1.f;
}

// ------- gram_x: symmetric, f16 input, 64x64 tile, BK=128, padded LDS -------
// grid 32x32 triangle -> 528 working blocks (~2/CU), 34.8 KB LDS.
__global__ __launch_bounds__(256) void gram_x_mfma_kernel(
    const _Float16* __restrict__ Xh, const float* __restrict__ sq,
    _Float16* __restrict__ K16) {
  const int bi = blockIdx.x, bj = blockIdx.y;
  if (bj < bi) return;  // symmetry: upper triangle only
  __shared__ _Float16 Ah[64][136];  // 272 B stride, 16B-aligned
  __shared__ _Float16 Bh[64][136];
  const int i0 = bi * 64, j0 = bj * 64;
  const int t = threadIdx.x;
  const int lane = t & 63, w = t >> 6;
  const int wm = (w & 1) * 32, wn = (w >> 1) * 32;
  const int m = lane & 15, q = lane >> 4;
  f32x4 acc[2][2];
  #pragma unroll
  for (int a = 0; a < 2; a++)
    #pragma unroll
    for (int b = 0; b < 2; b++) acc[a][b] = (f32x4){0.f, 0.f, 0.f, 0.f};

  for (int k0 = 0; k0 < DX; k0 += 128) {
    __syncthreads();  // protect previous round's readers
    #pragma unroll
    for (int r = 0; r < 4; r++) {
      const int fidx = t + r * 256;
      const int row = fidx >> 4, c8 = (fidx & 15) << 3;
      f16x8 va = *(const f16x8*)(Xh + (size_t)(i0 + row) * DX + k0 + c8);
      f16x8 vb = *(const f16x8*)(Xh + (size_t)(j0 + row) * DX + k0 + c8);
      *(f16x8*)&Ah[row][c8] = va;
      *(f16x8*)&Bh[row][c8] = vb;
    }
    __syncthreads();
    #pragma unroll
    for (int kk = 0; kk < 4; kk++) {
      f16x8 af[2], bf[2];
      #pragma unroll
      for (int mt = 0; mt < 2; mt++)
        af[mt] = *(const f16x8*)&Ah[wm + mt * 16 + m][kk * 32 + q * 8];
      #pragma unroll
      for (int nt = 0; nt < 2; nt++)
        bf[nt] = *(const f16x8*)&Bh[wn + nt * 16 + m][kk * 32 + q * 8];
      #pragma unroll
      for (int mt = 0; mt < 2; mt++)
        #pragma unroll
        for (int nt = 0; nt < 2; nt++)
          acc[mt][nt] = __builtin_amdgcn_mfma_f32_16x16x32_f16(af[mt], bf[nt], acc[mt][nt], 0, 0, 0);
    }
  }
  const float inv2s2 = 0.02f;  // 1/(2*5^2)
  #pragma unroll
  for (int mt = 0; mt < 2; mt++) {
    #pragma unroll
    for (int nt = 0; nt < 2; nt++) {
      const int col = j0 + wn + nt * 16 + m;
      const float sj = sq[col];
      #pragma unroll
      for (int reg = 0; reg < 4; reg++) {
        const int row = i0 + wm + mt * 16 + q * 4 + reg;
        float d2 = fmaxf(sq[row] + sj - 2.0f * acc[mt][nt][reg], 0.f);
        float kv = __expf(-d2 * inv2s2);
        if (row == col) kv = 1.0f;
        K16[(size_t)row * NN + col] = (_Float16)kv;
        if (bi != bj) K16[(size_t)col * NN + row] = (_Float16)kv;  // mirror
      }
    }
  }
}

// ---------------- gram_e, f16 output ----------------
__global__ __launch_bounds__(256) void gram_e_kernel(
    const float* __restrict__ e, _Float16* __restrict__ K16) {
  __shared__ float Ei[64][DE];
  __shared__ float Ej[64][DE];
  const int i0 = blockIdx.x * 64, j0 = blockIdx.y * 64;
  const int t = threadIdx.x;
  for (int idx = t; idx < 64 * DE; idx += 256) {
    int r = idx / DE, d = idx - r * DE;
    Ei[r][d] = e[(size_t)(i0 + r) * DE + d];
    Ej[r][d] = e[(size_t)(j0 + r) * DE + d];
  }
  __syncthreads();
  const int pi = t >> 4, pj = t & 15;
  float acc[4][4] = {};
  #pragma unroll
  for (int d = 0; d < DE; d++) {
    float a[4], b[4];
    #pragma unroll
    for (int ii = 0; ii < 4; ii++) a[ii] = Ei[(pi << 2) + ii][d];
    #pragma unroll
    for (int jj = 0; jj < 4; jj++) b[jj] = Ej[(pj << 2) + jj][d];
    #pragma unroll
    for (int ii = 0; ii < 4; ii++)
      #pragma unroll
      for (int jj = 0; jj < 4; jj++) {
        float df = a[ii] - b[jj];
        acc[ii][jj] = fmaf(df, df, acc[ii][jj]);
      }
  }
  #pragma unroll
  for (int ii = 0; ii < 4; ii++) {
    const int i = i0 + (pi << 2) + ii;
    const int jb = j0 + (pj << 2);
    f16x4 o = { (_Float16)__expf(-0.5f * acc[ii][0]),
                (_Float16)__expf(-0.5f * acc[ii][1]),
                (_Float16)__expf(-0.5f * acc[ii][2]),
                (_Float16)__expf(-0.5f * acc[ii][3]) };
    *(f16x4*)(K16 + (size_t)i * NN + jb) = o;
  }
}

// ------- KC = KA.*KB + per-row Gershgorin sums (atomic-free, 3 mats) --------
__global__ __launch_bounds__(256) void kc_rowsums_kernel(
    const _Float16* __restrict__ KA16, const _Float16* __restrict__ KB16,
    _Float16* __restrict__ KC16, float* __restrict__ rows) {
  const int i = blockIdx.x, t = threadIdx.x;
  const size_t base = (size_t)i * NN + t * 8;
  f16x8 a = *(const f16x8*)(KA16 + base);
  f16x8 b = *(const f16x8*)(KB16 + base);
  f16x8 cp;
  float sA = 0.f, sB = 0.f, sC = 0.f;
  #pragma unroll
  for (int e = 0; e < 8; e++) {
    float fa = (float)a[e], fb = (float)b[e];
    float fc = fa * fb;
    cp[e] = (_Float16)fc;
    sA += fa; sB += fb; sC += fc;
  }
  *(f16x8*)(KC16 + base) = cp;
  #pragma unroll
  for (int off = 32; off > 0; off >>= 1) {
    sA += __shfl_down(sA, off, 64);
    sB += __shfl_down(sB, off, 64);
    sC += __shfl_down(sC, off, 64);
  }
  __shared__ float rA[4], rB[4], rC[4];
  const int lane = t & 63, w = t >> 6;
  if (lane == 0) { rA[w] = sA; rB[w] = sB; rC[w] = sC; }
  __syncthreads();
  if (t == 0) {
    rows[i]          = rA[0] + rA[1] + rA[2] + rA[3];
    rows[NN + i]     = rB[0] + rB[1] + rB[2] + rB[3];
    rows[2 * NN + i] = rC[0] + rC[1] + rC[2] + rC[3];
  }
}

// single block: max over per-row sums -> Gershgorin radii
__global__ __launch_bounds__(256) void rmax_kernel(
    const float* __restrict__ rows, unsigned* __restrict__ Rbits) {
  const int t = threadIdx.x;
  float m0 = 0.f, m1 = 0.f, m2 = 0.f;
  for (int i = t; i < NN; i += 256) {
    m0 = fmaxf(m0, rows[i]);
    m1 = fmaxf(m1, rows[NN + i]);
    m2 = fmaxf(m2, rows[2 * NN + i]);
  }
  #pragma unroll
  for (int off = 32; off > 0; off >>= 1) {
    m0 = fmaxf(m0, __shfl_down(m0, off, 64));
    m1 = fmaxf(m1, __shfl_down(m1, off, 64));
    m2 = fmaxf(m2, __shfl_down(m2, off, 64));
  }
  __shared__ float rA[4], rB[4], rC[4];
  const int lane = t & 63, w = t >> 6;
  if (lane == 0) { rA[w] = m0; rB[w] = m1; rC[w] = m2; }
  __syncthreads();
  if (t == 0) {  // 1.0005 safety: f16 storage rounding + f32 sum rounding
    Rbits[0] = __float_as_uint(fmaxf(fmaxf(rA[0], rA[1]), fmaxf(rA[2], rA[3])) * 1.0005f);
    Rbits[1] = __float_as_uint(fmaxf(fmaxf(rB[0], rB[1]), fmaxf(rB[2], rB[3])) * 1.0005f);
    Rbits[2] = __float_as_uint(fmaxf(fmaxf(rC[0], rC[1]), fmaxf(rC[2], rC[3])) * 1.0005f);
  }
}

// ---------------- Chebyshev coefficients (parallel fp64 DCT) ----------------
__global__ __launch_bounds__(256) void cheb_coeffs_kernel(
    const unsigned* __restrict__ Rbits, float* __restrict__ c) {
  const int bx = blockIdx.x;  // 0 .. 3*NCOEF-1
  const int matm = bx / NCOEF, k = bx - matm * NCOEF;
  const double R = (double)__uint_as_float(Rbits[matm]);
  const double PI = 3.14159265358979323846;
  const int t = threadIdx.x;
  double sum = 0.0;
  #pragma unroll
  for (int r = 0; r < 2; r++) {
    const int j = t + 256 * r;
    double th = PI * (j + 0.5) / 512.0;
    double xx = R * (cos(th) + 1.0) * 0.5;
    double f = (xx > 0.0) ? xx * log(xx) : 0.0;
    sum += f * cos(th * (double)k);
  }
  #pragma unroll
  for (int off = 32; off > 0; off >>= 1) sum += __shfl_down(sum, off, 64);
  __shared__ double red[4];
  const int lane = t & 63, w = t >> 6;
  if (lane == 0) red[w] = sum;
  __syncthreads();
  if (t == 0) {
    double ck = (red[0] + red[1] + red[2] + red[3]) * (2.0 / 512.0);
    if (k == 0) ck *= 0.5;
    c[matm * NCOEF + k] = (float)ck;
  }
}

// ---------------- fused Chebyshev step ----------------
// Dispatch D_k: reconstruct W_k from Pprev + ring (k>=1), stage to LDS f16,
// compute partial P_k = K * W_k via MFMA. blockIdx.x==0 blocks write W_k to
// ring and accumulate SsA[k]=<Wk,Wk>, SsB[k]=<Wk,Wk-1> (moment doubling).
// Grid (32 i-tiles x 8 j-chunks x 3 mats) = 768 blocks, 256 threads.
// Ring slot: [mat][p][2048] f32 (98304/slot). P: [mat*8+chunk][p][i] f32.
__global__ __launch_bounds__(256) void cheb_fused_kernel(
    const _Float16* __restrict__ KA16, const _Float16* __restrict__ KB16,
    const _Float16* __restrict__ KC16,
    const float* __restrict__ Pprev, float* __restrict__ Pcur,
    const float* __restrict__ Wcur, const float* __restrict__ Wprev,
    float* __restrict__ Wout,
    const unsigned* __restrict__ Rbits, float* __restrict__ SsA,
    float* __restrict__ SsB, int k, float fnum, float beta, float gamma) {
  __shared__ _Float16 Wlds[16][264];  // 528 B stride (16B-aligned)
  const int mat = blockIdx.z;
  const int i0 = blockIdx.x * 64;
  const int j0 = blockIdx.y * JSZ;
  const int t = threadIdx.x;
  const int s = t & 15, p = t >> 4;

  if (k > 0) {
    const float R = __uint_as_float(Rbits[mat]);
    const float alpha = fnum / R;
    const size_t wbase = ((size_t)mat * 16 + p) * NN;
    float dA = 0.f, dB = 0.f;
    #pragma unroll
    for (int u = 0; u < 4; u++) {
      const int jl = s * 4 + u * 64;
      const size_t jg = j0 + jl;
      float4 y = {0.f, 0.f, 0.f, 0.f};
      #pragma unroll
      for (int c = 0; c < JCHUNK; c++) {
        const float4 pv = *(const float4*)(
            Pprev + (((size_t)(mat * JCHUNK + c) * 16 + p) << 11) + jg);
        y.x += pv.x; y.y += pv.y; y.z += pv.z; y.w += pv.w;
      }
      const float4 wc = *(const float4*)(Wcur + wbase + jg);
      const float4 wp = *(const float4*)(Wprev + wbase + jg);
      float4 wv;
      wv.x = alpha * y.x + beta * wc.x + gamma * wp.x;
      wv.y = alpha * y.y + beta * wc.y + gamma * wp.y;
      wv.z = alpha * y.z + beta * wc.z + gamma * wp.z;
      wv.w = alpha * y.w + beta * wc.w + gamma * wp.w;
      f16x4 h = { (_Float16)wv.x, (_Float16)wv.y, (_Float16)wv.z, (_Float16)wv.w };
      *(f16x4*)&Wlds[p][jl] = h;
      dA += wv.x * wv.x + wv.y * wv.y + wv.z * wv.z + wv.w * wv.w;
      dB += wv.x * wc.x + wv.y * wc.y + wv.z * wc.z + wv.w * wc.w;
      if (blockIdx.x == 0) *(float4*)(Wout + wbase + jg) = wv;
    }
    #pragma unroll
    for (int off = 32; off > 0; off >>= 1) {
      dA += __shfl_down(dA, off, 64);
      dB += __shfl_down(dB, off, 64);
    }
    __shared__ float rA[4], rB[4];
    const int lane = t & 63, w = t >> 6;
    if (lane == 0) { rA[w] = dA; rB[w] = dB; }
    __syncthreads();  // also orders Wlds writes before phase 2
    if (t == 0 && blockIdx.x == 0) {
      atomicAdd(&SsA[mat * (MSTEP + 1) + k], rA[0] + rA[1] + rA[2] + rA[3]);
      atomicAdd(&SsB[mat * (MSTEP + 1) + k], rB[0] + rB[1] + rB[2] + rB[3]);
    }
  } else {
    // k == 0: W_0 = V directly from ring slot (f32 +-1)
    const size_t wbase = ((size_t)mat * 16 + p) * NN;
    #pragma unroll
    for (int u = 0; u < 4; u++) {
      const int jl = s * 4 + u * 64;
      const float4 wv = *(const float4*)(Wcur + wbase + j0 + jl);
      f16x4 h = { (_Float16)wv.x, (_Float16)wv.y, (_Float16)wv.z, (_Float16)wv.w };
      *(f16x4*)&Wlds[p][jl] = h;
    }
    __syncthreads();
  }

  // phase 2: MFMA gemm over this (i-tile, j-chunk)
  const int w = t >> 6, lane = t & 63;
  const int m = lane & 15, q = lane >> 4;
  const _Float16* Kp = (mat == 0) ? KA16 : ((mat == 1) ? KB16 : KC16);
  const size_t rowoff = (size_t)(i0 + w * 16 + m) * NN + j0;
  f32x4 acc = {0.f, 0.f, 0.f, 0.f};
  #pragma unroll
  for (int st = 0; st < 8; st++) {
    const int jb = st * 32 + q * 8;
    f16x8 a = *(const f16x8*)(Kp + rowoff + jb);
    f16x8 b = *(const f16x8*)&Wlds[m][jb];
    acc = __builtin_amdgcn_mfma_f32_16x16x32_f16(a, b, acc, 0, 0, 0);
  }
  float4 stv = {acc[0], acc[1], acc[2], acc[3]};
  *(float4*)(Pcur + (((size_t)(mat * JCHUNK + blockIdx.y) * 16 + m) << 11) +
             i0 + w * 16 + q * 4) = stv;
}

// ---------------- tail: dots for k = MSTEP (no gemm) ----------------
__global__ __launch_bounds__(256) void cheb_tail_kernel(
    const float* __restrict__ P, const float* __restrict__ Wcur,
    const float* __restrict__ Wprev, const unsigned* __restrict__ Rbits,
    float* __restrict__ SsA, float* __restrict__ SsB) {
  const int idx = blockIdx.x * 256 + threadIdx.x;  // 384*256 = 98304 exact
  const int mat = idx >> 15;
  const int inner = idx & 32767;
  const float R = __uint_as_float(Rbits[mat]);
  const float alpha = 4.f / R;
  float y = 0.f;
  #pragma unroll
  for (int c = 0; c < JCHUNK; c++)
    y += P[(((size_t)mat * JCHUNK + c) << 15) + inner];
  const float wc = Wcur[idx];
  const float wv = alpha * y - 2.f * wc - Wprev[idx];
  float dA = wv * wv, dB = wv * wc;
  #pragma unroll
  for (int off = 32; off > 0; off >>= 1) {
    dA += __shfl_down(dA, off, 64);
    dB += __shfl_down(dB, off, 64);
  }
  __shared__ float rA[4], rB[4];
  const int lane = threadIdx.x & 63, w = threadIdx.x >> 6;
  if (lane == 0) { rA[w] = dA; rB[w] = dB; }
  __syncthreads();
  if (threadIdx.x == 0) {
    atomicAdd(&SsA[mat * (MSTEP + 1) + MSTEP], rA[0] + rA[1] + rA[2] + rA[3]);
    atomicAdd(&SsB[mat * (MSTEP + 1) + MSTEP], rB[0] + rB[1] + rB[2] + rB[3]);
  }
}

// ---------------- finalize ----------------
__global__ __launch_bounds__(64) void finalize_kernel(
    const float* __restrict__ c, const float* __restrict__ SsA,
    const float* __restrict__ SsB, float* __restrict__ out) {
  if (threadIdx.x != 0) return;
  const double mu0 = (double)NN * (double)SPROBE;
  double D[3];
  for (int m = 0; m < 3; m++) {
    const float* cm = c + m * NCOEF;
    const double mu1 = (double)SsB[m * (MSTEP + 1) + 1];  // mu1 == <W1,W0>
    double d = (double)cm[0] * mu0 + (double)cm[1] * mu1;
    for (int k = 1; k <= MSTEP; k++) {
      const double muE = 2.0 * (double)SsA[m * (MSTEP + 1) + k] - mu0;
      d += (double)cm[2 * k] * muE;
      if (k >= 2) {
        const double muO = 2.0 * (double)SsB[m * (MSTEP + 1) + k] - mu1;
        d += (double)cm[2 * k - 1] * muO;
      }
    }
    D[m] = d / mu0;
  }
  out[0] = (float)(log((double)NN) - D[0] - D[1] + D[2]);
}

__global__ void fallback_kernel(float* out) { out[0] = logf((float)NN); }

// ---------------- host orchestration ----------------
extern "C" void kernel_launch(void* const* d_in, const int* in_sizes, int n_in,
                              void* d_out, int out_size, void* d_ws, size_t ws_size,
                              hipStream_t stream) {
  const float* x    = (const float*)d_in[0];
  const float* outs = (const float*)d_in[1];
  const float* tgts = (const float*)d_in[2];

  // float-unit offsets; total 9,240,576 floats = 36.96 MB
  const size_t NEEDED = 9240576ull * sizeof(float);
  if (ws_size < NEEDED) {
    fallback_kernel<<<1, 64, 0, stream>>>((float*)d_out);
    return;
  }
  float* ws = (float*)d_ws;
  float* SsA = ws;                           // [3*9] pad 128
  float* SsB = ws + 128;                     // [3*9] pad 128
  unsigned* Rbits = (unsigned*)(ws + 256);   // [3] pad 32
  float* cbuf = ws + 288;                    // [3*17=51] -> ends 339
  float* sqx  = ws + 512;                    // [2048]
  float* ebuf = ws + 2560;                   // [20480] -> ends 23040
  float* rows = ws + 24576;                  // [3*2048] -> ends 30720
  float* Wring = ws + 32768;                 // 3 x 98304 -> ends 327680
  float* Pb[2] = { ws + 327680, ws + 1114112 };  // 2 x 786432 -> ends 1900544
  _Float16* Xh = (_Float16*)(ws + 1900544);      // 6291456 halves (3145728 f)
  _Float16* KC16 = Xh;                           // aliases Xh (Xh dead by then)
  _Float16* KA16 = (_Float16*)(ws + 5046272);    // 4194304 halves each
  _Float16* KB16 = KA16 + (size_t)NN * NN;       // ends 9240576

  hipMemsetAsync(d_ws, 0, 1152, stream);  // SsA, SsB, Rbits
  compute_e_kernel<<<80, 256, 0, stream>>>(outs, tgts, ebuf);
  prep_x_kernel<<<NN, 256, 0, stream>>>(x, sqx, Xh);
  gram_x_mfma_kernel<<<dim3(32, 32), 256, 0, stream>>>(Xh, sqx, KA16);
  gram_e_kernel<<<dim3(32, 32), 256, 0, stream>>>(ebuf, KB16);
  kc_rowsums_kernel<<<NN, 256, 0, stream>>>(KA16, KB16, KC16, rows);
  rmax_kernel<<<1, 256, 0, stream>>>(rows, Rbits);
  cheb_coeffs_kernel<<<3 * NCOEF, 256, 0, stream>>>(Rbits, cbuf);
  fill_rademacher_kernel<<<384, 256, 0, stream>>>(Wring);  // ring slot 0 = W_0

  for (int k = 0; k < MSTEP; k++) {
    const float fnum  = (k == 1) ? 2.f : 4.f;
    const float beta  = (k == 1) ? -1.f : -2.f;
    const float gamma = (k <= 1) ? 0.f : -1.f;
    const int scur = (k == 0) ? 0 : (k - 1) % 3;   // W_{k-1} slot (W_0 for k=0)
    const int sprev = (k <= 1) ? 0 : (k - 2) % 3;  // W_{k-2} slot (dummy if gamma=0)
    cheb_fused_kernel<<<dim3(32, JCHUNK, 3), 256, 0, stream>>>(
        KA16, KB16, KC16, Pb[(k + 1) & 1], Pb[k & 1],
        Wring + (size_t)scur * 98304, Wring + (size_t)sprev * 98304,
        Wring + (size_t)(k % 3) * 98304,
        Rbits, SsA, SsB, k, fnum, beta, gamma);
  }
  // tail k=8: P_7 in Pb[7&1]=Pb[1]; W_7 = ring[7%3=1], W_6 = ring[6%3=0]
  cheb_tail_kernel<<<384, 256, 0, stream>>>(
      Pb[1], Wring + 98304, Wring, Rbits, SsA, SsB);
  finalize_kernel<<<1, 64, 0, stream>>>(cbuf, SsA, SsB, (float*)d_out);
}